// Round 23
// baseline (148.843 us; speedup 1.0000x reference)
//
#include <hip/hip_runtime.h>
#include <hip/hip_bf16.h>

typedef short s16x8 __attribute__((ext_vector_type(8)));
typedef float f32x4 __attribute__((ext_vector_type(4)));
typedef float f32x16 __attribute__((ext_vector_type(16)));
typedef unsigned int u32;
typedef unsigned int u32x4 __attribute__((ext_vector_type(4)));
typedef unsigned short u16x4 __attribute__((ext_vector_type(4)));
typedef unsigned long long u64;

#define LOG2E 1.4426950408889634f
#define QSCALE 0.18033688011112042f  // 0.125 * log2(e)
#define NEG_BIG -3.0e38f

#define PKS(dst, a, b) asm("v_cvt_pk_bf16_f32 %0, %1, %2" : "=v"(dst) : "v"(a), "v"(b))
#define SWP(x, y) asm("v_permlane32_swap_b32 %0, %1" : "+v"(x), "+v"(y))

__device__ __forceinline__ unsigned short f2b(float f) {
    unsigned int u = __float_as_uint(f);
    unsigned int r = (u + 0x7fffu + ((u >> 16) & 1u)) >> 16;
    return (unsigned short)r;
}

__device__ __forceinline__ void g2l16(const void* g, void* l) {
    __builtin_amdgcn_global_load_lds(
        (const __attribute__((address_space(1))) unsigned int*)(g),
        (__attribute__((address_space(3))) unsigned int*)(l), 16, 0, 0);
}

// ---------------- weight prep: Wqkv^T, Wout^T, bias table ----------------
// r22: bias table pre-shifted by -8 (fixed softmax reference; no running max).
__global__ __launch_bounds__(256) void k_prepw(const float* __restrict__ Wqkv,
                                               unsigned short* __restrict__ wqkvT,
                                               const float* __restrict__ Wout,
                                               unsigned short* __restrict__ woutT,
                                               const float* __restrict__ W1,
                                               const float* __restrict__ b1,
                                               const float* __restrict__ W2,
                                               float* __restrict__ btab) {
    int bid = blockIdx.x, tid = threadIdx.x;
    {
        int idx = bid * 256 + tid;           // 786432 elements
        int k = idx & 511, n = idx >> 9;
        wqkvT[idx] = f2b(Wqkv[(long)k * 1536 + n]);
    }
    if (bid < 1024) {
        int idx = bid * 256 + tid;           // 262144 elements
        int k = idx & 511, n = idx >> 9;
        woutT[idx] = f2b(Wout[(long)k * 512 + n]);
    }
    if (bid >= 3064) {
        int idx = (bid - 3064) * 256 + tid;  // 0..2047
        if (idx <= 2045) {
            float t = 0.0f;
            if (idx != 2045) {
                float r = (float)(idx - 1022) * (8.0f / 1022.0f);
                float sg = (r > 0.f) ? 1.0f : ((r < 0.f) ? -1.0f : 0.0f);
                t = sg * log2f(fabsf(r) + 1.0f) * 0.3154648767971406f;  // 1/log2(9)
            }
            float acc[8] = {0, 0, 0, 0, 0, 0, 0, 0};
            float accc[8] = {0, 0, 0, 0, 0, 0, 0, 0};
            for (int j = 0; j < 64; ++j) {
                float hj = t * W1[j] + b1[j];
                hj = (hj > 0.f) ? hj : 0.2f * hj;
                float hc = b1[j];
                hc = (hc > 0.f) ? hc : 0.2f * hc;
                #pragma unroll
                for (int h = 0; h < 8; ++h) {
                    acc[h] += hj * W2[j * 8 + h];
                    accc[h] += hc * W2[j * 8 + h];
                }
            }
            #pragma unroll
            for (int h = 0; h < 8; ++h) {
                btab[h * 4096 + idx] = acc[h] * LOG2E - 8.0f;
                btab[h * 4096 + 2048 + idx] = accc[h] * LOG2E - 8.0f;
            }
        }
    }
}

// ---------------- GEMM: C = A @ BT^T, bf16 MFMA ----------------
template <int MODE>
__global__ __launch_bounds__(256) void k_gemm(const float* __restrict__ Af,
                                              const unsigned short* __restrict__ A16,
                                              const unsigned short* __restrict__ BT,
                                              int M, int N,
                                              unsigned short* __restrict__ Qp,
                                              unsigned short* __restrict__ Kp,
                                              unsigned short* __restrict__ VTp,
                                              float* __restrict__ Cout) {
    __shared__ __align__(16) unsigned short As[2][128 * 32];
    __shared__ __align__(16) unsigned short Bs[2][128 * 32];
    constexpr int NX = (MODE == 0) ? 12 : 4;      // N/128
    constexpr int NWG = (MODE == 0) ? 1536 : 512; // total workgroups (div by 8)
    int lid = blockIdx.y * NX + blockIdx.x;       // linear dispatch index (x fastest)
    int tile = (lid & 7) * (NWG >> 3) + (lid >> 3);
    int m0 = (tile / NX) * 128, n0 = (tile % NX) * 128;
    int tid = threadIdx.x;
    int wave = tid >> 6, lane = tid & 63, lr = lane & 15, g = lane >> 4;
    int wr = wave >> 1, wc = wave & 1;
    f32x4 acc[4][4] = {};
    const float* Af0 = Af + (long)(m0 + (tid >> 2)) * 512 + (tid & 3) * 8;
    const float* Af1 = Af0 + 64 * 512;
    const char* Ab = (const char*)A16 + (long)(m0 + (tid >> 2)) * 1024 + (tid & 3) * 16;
    const char* Bb = (const char*)BT + (long)(n0 + (tid >> 2)) * 1024 + (tid & 3) * 16;

    // prologue: stage tile 0 into buffer 0
    if (MODE == 0) {
        f32x4 a0 = *(const f32x4*)(Af0);
        f32x4 a1 = *(const f32x4*)(Af0 + 4);
        f32x4 a2 = *(const f32x4*)(Af1);
        f32x4 a3 = *(const f32x4*)(Af1 + 4);
        u32 w0, w1, w2, w3;
        PKS(w0, a0.x, a0.y); PKS(w1, a0.z, a0.w);
        PKS(w2, a1.x, a1.y); PKS(w3, a1.z, a1.w);
        *(u32x4*)((char*)As[0] + tid * 16) = u32x4{w0, w1, w2, w3};
        PKS(w0, a2.x, a2.y); PKS(w1, a2.z, a2.w);
        PKS(w2, a3.x, a3.y); PKS(w3, a3.z, a3.w);
        *(u32x4*)((char*)As[0] + 4096 + tid * 16) = u32x4{w0, w1, w2, w3};
    } else {
        g2l16(Ab, (char*)As[0] + wave * 1024);
        g2l16(Ab + 65536, (char*)As[0] + 4096 + wave * 1024);
    }
    g2l16(Bb, (char*)Bs[0] + wave * 1024);
    g2l16(Bb + 65536, (char*)Bs[0] + 4096 + wave * 1024);
    __syncthreads();

    for (int kt = 0; kt < 16; ++kt) {
        int cur = kt & 1;
        int nxt = cur ^ 1;
        f32x4 na0, na1, na2, na3;
        if (kt < 15) {
            if (MODE == 0) {
                na0 = *(const f32x4*)(Af0 + (kt + 1) * 32);
                na1 = *(const f32x4*)(Af0 + (kt + 1) * 32 + 4);
                na2 = *(const f32x4*)(Af1 + (kt + 1) * 32);
                na3 = *(const f32x4*)(Af1 + (kt + 1) * 32 + 4);
            } else {
                g2l16(Ab + (kt + 1) * 64, (char*)As[nxt] + wave * 1024);
                g2l16(Ab + 65536 + (kt + 1) * 64, (char*)As[nxt] + 4096 + wave * 1024);
            }
            g2l16(Bb + (kt + 1) * 64, (char*)Bs[nxt] + wave * 1024);
            g2l16(Bb + 65536 + (kt + 1) * 64, (char*)Bs[nxt] + 4096 + wave * 1024);
        }
        s16x8 av[4], bv[4];
        #pragma unroll
        for (int f = 0; f < 4; ++f) {
            av[f] = *(const s16x8*)((char*)As[cur] + (wr * 64 + f * 16 + lr) * 64 + g * 16);
            bv[f] = *(const s16x8*)((char*)Bs[cur] + (wc * 64 + f * 16 + lr) * 64 + g * 16);
        }
        __builtin_amdgcn_s_setprio(1);
        #pragma unroll
        for (int fi = 0; fi < 4; ++fi)
            #pragma unroll
            for (int fj = 0; fj < 4; ++fj)
                acc[fi][fj] = __builtin_amdgcn_mfma_f32_16x16x32_bf16(bv[fj], av[fi], acc[fi][fj], 0, 0, 0);
        __builtin_amdgcn_s_setprio(0);
        if (MODE == 0 && kt < 15) {
            u32 w0, w1, w2, w3;
            PKS(w0, na0.x, na0.y); PKS(w1, na0.z, na0.w);
            PKS(w2, na1.x, na1.y); PKS(w3, na1.z, na1.w);
            *(u32x4*)((char*)As[nxt] + tid * 16) = u32x4{w0, w1, w2, w3};
            PKS(w0, na2.x, na2.y); PKS(w1, na2.z, na2.w);
            PKS(w2, na3.x, na3.y); PKS(w3, na3.z, na3.w);
            *(u32x4*)((char*)As[nxt] + 4096 + tid * 16) = u32x4{w0, w1, w2, w3};
        }
        __syncthreads();
    }
    // epilogue (swapped layout): lane holds C[gm = m0+wr*64+fi*16+lr][n = n0+wc*64+fj*16+g*4+e]
    #pragma unroll
    for (int fi = 0; fi < 4; ++fi) {
        int gm = m0 + wr * 64 + fi * 16 + lr;
        if (MODE == 0) {
            int bq = gm >> 10, lp = gm & 1023;
            int kvt = lp >> 6, kvl = lp & 63;
            #pragma unroll
            for (int fj = 0; fj < 4; ++fj) {
                int col0 = n0 + wc * 64 + fj * 16 + g * 4;  // 4-aligned; sec/h constant over e
                int sec = col0 >> 9, c0 = col0 & 511, h = c0 >> 6, dd0 = c0 & 63;
                int bh = bq * 8 + h;
                float v0 = acc[fi][fj][0], v1 = acc[fi][fj][1];
                float v2 = acc[fi][fj][2], v3 = acc[fi][fj][3];
                if (sec == 0) {
                    u32 w0, w1;
                    float q0 = v0 * QSCALE, q1 = v1 * QSCALE, q2 = v2 * QSCALE, q3 = v3 * QSCALE;
                    PKS(w0, q0, q1); PKS(w1, q2, q3);
                    *(uint2*)(Qp + (long)(bh * 1024 + lp) * 64 + dd0) = make_uint2(w0, w1);
                } else if (sec == 1) {
                    u32 w0, w1;
                    PKS(w0, v0, v1); PKS(w1, v2, v3);
                    long off = (long)bh * 65536 + kvt * 4096 + (kvl >> 5) * 2048 +
                               (dd0 >> 4) * 512 + ((((dd0 >> 3) & 1) << 5) + (kvl & 31)) * 8 + (dd0 & 7);
                    *(uint2*)(Kp + off) = make_uint2(w0, w1);
                } else {
                    // VT fragment-linear: consecutive dd -> stride 8 shorts
                    long off = (long)bh * 65536 + kvt * 4096 + (dd0 >> 5) * 2048 +
                               (kvl >> 4) * 512 + ((((kvl >> 3) & 1) << 5) + (dd0 & 31)) * 8 + (kvl & 7);
                    VTp[off] = f2b(v0);
                    VTp[off + 8] = f2b(v1);
                    VTp[off + 16] = f2b(v2);
                    VTp[off + 24] = f2b(v3);
                }
            }
        } else {
            #pragma unroll
            for (int fj = 0; fj < 4; ++fj) {
                int col0 = n0 + wc * 64 + fj * 16 + g * 4;
                *(f32x4*)(Cout + (long)gm * N + col0) = acc[fi][fj];
            }
        }
    }
}

// ---------------- flash attention ----------------
// r22 frame + r23: one-tile-deep S pipeline (att[2]). Fixed-reference softmax has
// no cross-tile state, so iter t issues QK(t) into one S-set and runs
// softmax+pack+PV for tile t-1 on the other set — the QK-result wait leaves the
// critical path. Two named S sets (sA/sB) alternate by parity; ops identical and
// in the same mathematical order -> bitwise-same output as r22.
#define ATT_STAGE(MTT) do { \
    char* Kn_ = smem + ((MTT) % 3) * 16384; \
    g2l16(Kg + (MTT) * 8192 + tid * 16, Kn_ + wave * 1024); \
    g2l16(Vg + (MTT) * 8192 + tid * 16, Kn_ + 8192 + wave * 1024); \
  } while (0)

#define ATT_QK(MT, S0, S1) do { \
    if ((MT) + 1 < 16) ATT_STAGE((MT) + 1); \
    char* Kl = smem + ((MT) % 3) * 16384; \
    f32x16 t0_ = {}, t1_ = {}; \
    __builtin_amdgcn_s_setprio(1); \
    t0_ = __builtin_amdgcn_mfma_f32_32x32x16_bf16(*(const s16x8*)(Kl + lx), qf0, t0_, 0, 0, 0); \
    t0_ = __builtin_amdgcn_mfma_f32_32x32x16_bf16(*(const s16x8*)(Kl + 1024 + lx), qf1, t0_, 0, 0, 0); \
    t0_ = __builtin_amdgcn_mfma_f32_32x32x16_bf16(*(const s16x8*)(Kl + 2048 + lx), qf2, t0_, 0, 0, 0); \
    t0_ = __builtin_amdgcn_mfma_f32_32x32x16_bf16(*(const s16x8*)(Kl + 3072 + lx), qf3, t0_, 0, 0, 0); \
    t1_ = __builtin_amdgcn_mfma_f32_32x32x16_bf16(*(const s16x8*)(Kl + 4096 + lx), qf0, t1_, 0, 0, 0); \
    t1_ = __builtin_amdgcn_mfma_f32_32x32x16_bf16(*(const s16x8*)(Kl + 5120 + lx), qf1, t1_, 0, 0, 0); \
    t1_ = __builtin_amdgcn_mfma_f32_32x32x16_bf16(*(const s16x8*)(Kl + 6144 + lx), qf2, t1_, 0, 0, 0); \
    t1_ = __builtin_amdgcn_mfma_f32_32x32x16_bf16(*(const s16x8*)(Kl + 7168 + lx), qf3, t1_, 0, 0, 0); \
    __builtin_amdgcn_s_setprio(0); \
    S0 = t0_; S1 = t1_; \
  } while (0)

#define ATT_PV(VPTR) do { \
    __builtin_amdgcn_s_setprio(1); \
    o0 = __builtin_amdgcn_mfma_f32_32x32x16_bf16(*(const s16x8*)((VPTR) + lx), Pc0, o0, 0, 0, 0); \
    o0 = __builtin_amdgcn_mfma_f32_32x32x16_bf16(*(const s16x8*)((VPTR) + 1024 + lx), Pc1, o0, 0, 0, 0); \
    o0 = __builtin_amdgcn_mfma_f32_32x32x16_bf16(*(const s16x8*)((VPTR) + 2048 + lx), Pc2, o0, 0, 0, 0); \
    o0 = __builtin_amdgcn_mfma_f32_32x32x16_bf16(*(const s16x8*)((VPTR) + 3072 + lx), Pc3, o0, 0, 0, 0); \
    o1 = __builtin_amdgcn_mfma_f32_32x32x16_bf16(*(const s16x8*)((VPTR) + 4096 + lx), Pc0, o1, 0, 0, 0); \
    o1 = __builtin_amdgcn_mfma_f32_32x32x16_bf16(*(const s16x8*)((VPTR) + 5120 + lx), Pc1, o1, 0, 0, 0); \
    o1 = __builtin_amdgcn_mfma_f32_32x32x16_bf16(*(const s16x8*)((VPTR) + 6144 + lx), Pc2, o1, 0, 0, 0); \
    o1 = __builtin_amdgcn_mfma_f32_32x32x16_bf16(*(const s16x8*)((VPTR) + 7168 + lx), Pc3, o1, 0, 0, 0); \
    __builtin_amdgcn_s_setprio(0); \
  } while (0)

// softmax + pack + PV for tile MTP on S-set (S0,S1)
#define ATT_SM(MTP, S0, S1) do { \
    int ib = (MTP) * 64 - l + 1022; \
    float b0[16], b1v[16]; \
    { \
        const float* bq = bp + ib + 4 * hi; \
        _Pragma("unroll") \
        for (int k = 0; k < 4; ++k) { \
            f32x4 va = *(const f32x4*)(bq + 8 * k); \
            f32x4 vb = *(const f32x4*)(bq + 32 + 8 * k); \
            b0[4 * k + 0] = va.x; b0[4 * k + 1] = va.y; \
            b0[4 * k + 2] = va.z; b0[4 * k + 3] = va.w; \
            b1v[4 * k + 0] = vb.x; b1v[4 * k + 1] = vb.y; \
            b1v[4 * k + 2] = vb.z; b1v[4 * k + 3] = vb.w; \
        } \
    } \
    u64 mb = *(const u64*)(smem + 49152 + (MTP) * 8); \
    u32 wm0 = (u32)(mb >> (4 * hi)); \
    u32 wm1 = (u32)(mb >> (32 + 4 * hi)); \
    if ((MTP) == 0 && hi == 0) b0[0] = c2; \
    _Pragma("unroll") \
    for (int r = 0; r < 16; ++r) { \
        int pos = (r & 3) + 8 * (r >> 2); \
        S0[r] = ((wm0 >> pos) & 1) ? S0[r] + b0[r] : NEG_BIG; \
        S1[r] = ((wm1 >> pos) & 1) ? S1[r] + b1v[r] : NEG_BIG; \
    } \
    _Pragma("unroll") \
    for (int r = 0; r < 16; ++r) S0[r] = __builtin_amdgcn_exp2f(S0[r]); \
    _Pragma("unroll") \
    for (int r = 0; r < 16; ++r) S1[r] = __builtin_amdgcn_exp2f(S1[r]); \
    { \
        float u0 = S0[0] + S0[1], u1 = S0[2] + S0[3], u2 = S0[4] + S0[5], u3 = S0[6] + S0[7]; \
        float u4 = S0[8] + S0[9], u5 = S0[10] + S0[11], u6 = S0[12] + S0[13], u7 = S0[14] + S0[15]; \
        float v0 = S1[0] + S1[1], v1 = S1[2] + S1[3], v2 = S1[4] + S1[5], v3 = S1[6] + S1[7]; \
        float v4 = S1[8] + S1[9], v5 = S1[10] + S1[11], v6 = S1[12] + S1[13], v7 = S1[14] + S1[15]; \
        u0 += u1; u2 += u3; u4 += u5; u6 += u7; \
        v0 += v1; v2 += v3; v4 += v5; v6 += v7; \
        u0 += u2; u4 += u6; v0 += v2; v4 += v6; \
        float ts = (u0 + u4) + (v0 + v4); \
        ts += __shfl_xor(ts, 32); \
        Ss += ts; \
    } \
    { \
        u32 x, y, x2, y2; \
        union { u32 w[4]; s16x8 v; } pt; \
        PKS(x, S0[0], S0[1]);  PKS(y, S0[4], S0[5]);  SWP(x, y); \
        PKS(x2, S0[2], S0[3]); PKS(y2, S0[6], S0[7]); SWP(x2, y2); \
        pt.w[0] = x; pt.w[1] = x2; pt.w[2] = y; pt.w[3] = y2; Pc0 = pt.v; \
        PKS(x, S0[8], S0[9]);   PKS(y, S0[12], S0[13]);  SWP(x, y); \
        PKS(x2, S0[10], S0[11]); PKS(y2, S0[14], S0[15]); SWP(x2, y2); \
        pt.w[0] = x; pt.w[1] = x2; pt.w[2] = y; pt.w[3] = y2; Pc1 = pt.v; \
        PKS(x, S1[0], S1[1]);  PKS(y, S1[4], S1[5]);  SWP(x, y); \
        PKS(x2, S1[2], S1[3]); PKS(y2, S1[6], S1[7]); SWP(x2, y2); \
        pt.w[0] = x; pt.w[1] = x2; pt.w[2] = y; pt.w[3] = y2; Pc2 = pt.v; \
        PKS(x, S1[8], S1[9]);   PKS(y, S1[12], S1[13]);  SWP(x, y); \
        PKS(x2, S1[10], S1[11]); PKS(y2, S1[14], S1[15]); SWP(x2, y2); \
        pt.w[0] = x; pt.w[1] = x2; pt.w[2] = y; pt.w[3] = y2; Pc3 = pt.v; \
    } \
    { \
        char* Vp_ = smem + ((MTP) % 3) * 16384 + 8192; \
        ATT_PV(Vp_); \
    } \
  } while (0)

#define ATT_IT(MT, SC0, SC1, SP0, SP1) do { \
    ATT_QK(MT, SC0, SC1); \
    ATT_SM((MT) - 1, SP0, SP1); \
    __syncthreads(); \
  } while (0)

__global__ __launch_bounds__(512, 2) void k_attn(const unsigned short* __restrict__ Q,
                                                 const unsigned short* __restrict__ Kb,
                                                 const unsigned short* __restrict__ VT,
                                                 const int* __restrict__ mask,
                                                 const float* __restrict__ btab,
                                                 unsigned short* __restrict__ AO) {
    __shared__ __align__(16) char smem[56320];  // 3x16K ring + mask @49152 + pad (cap=2/CU via LDS)
    int lid = blockIdx.x;
    int wg = (lid & 7) * 64 + (lid >> 3);   // bijective XCD swizzle (512 = 8*64)
    int qt = wg & 3, bh = wg >> 2;
    int b = bh >> 3, h = bh & 7;
    int tid = threadIdx.x;
    int wave = tid >> 6, lane = tid & 63;
    int q = lane & 31, hi = lane >> 5;
    int l = qt * 256 + wave * 32 + q;
    const float* bt = btab + h * 4096;
    float c2 = bt[2045];
    const float* bp = bt + ((l == 0) ? 2048 : 0);

    const char* Kg = (const char*)Kb + (long)bh * 131072;
    const char* Vg = (const char*)VT + (long)bh * 131072;

    // mask bitmasks -> LDS (one u64 per 64-kv tile)
    if (tid < 16) {
        const int* mrow = mask + b * 1023;
        u64 bits = 0;
        for (int j = 0; j < 64; ++j) {
            int kv = tid * 64 + j;
            int bit = (kv == 0) ? 1 : (mrow[kv - 1] != 0);
            bits |= (u64)bit << j;
        }
        *(u64*)(smem + 49152 + tid * 8) = bits;
    }

    // Q fragments (B-operand): col=q, k = d = ko*16 + hi*8 + e
    const char* Qrow = (const char*)Q + ((long)bh * 1024 + l) * 128;
    s16x8 qf0 = *(const s16x8*)(Qrow + 0 * 32 + hi * 16);
    s16x8 qf1 = *(const s16x8*)(Qrow + 1 * 32 + hi * 16);
    s16x8 qf2 = *(const s16x8*)(Qrow + 2 * 32 + hi * 16);
    s16x8 qf3 = *(const s16x8*)(Qrow + 3 * 32 + hi * 16);

    f32x16 o0 = {}, o1 = {};
    float Ss = 0.f;
    int lx = lane * 16;
    s16x8 Pc0 = {}, Pc1 = {}, Pc2 = {}, Pc3 = {};  // carried P (plain VGPR vectors)
    f32x16 sA0, sA1, sB0, sB1;                      // two S-sets (alternating)

    // prologue: stage tile 0 (ring slot 0)
    ATT_STAGE(0);
    __syncthreads();

    // t=0: QK only
    ATT_QK(0, sA0, sA1);
    __syncthreads();

    ATT_IT(1, sB0, sB1, sA0, sA1);   ATT_IT(2, sA0, sA1, sB0, sB1);
    ATT_IT(3, sB0, sB1, sA0, sA1);   ATT_IT(4, sA0, sA1, sB0, sB1);
    ATT_IT(5, sB0, sB1, sA0, sA1);   ATT_IT(6, sA0, sA1, sB0, sB1);
    ATT_IT(7, sB0, sB1, sA0, sA1);   ATT_IT(8, sA0, sA1, sB0, sB1);
    ATT_IT(9, sB0, sB1, sA0, sA1);   ATT_IT(10, sA0, sA1, sB0, sB1);
    ATT_IT(11, sB0, sB1, sA0, sA1);  ATT_IT(12, sA0, sA1, sB0, sB1);
    ATT_IT(13, sB0, sB1, sA0, sA1);  ATT_IT(14, sA0, sA1, sB0, sB1);
    ATT_IT(15, sB0, sB1, sA0, sA1);

    // tail: process tile 15 (written to sB at iter 15); V(15) in ring slot 0
    ATT_SM(15, sB0, sB1);
    __syncthreads();  // all waves done with ring reads before epilogue reuses LDS

    // epilogue: normalize, transpose via LDS, coalesced store
    float inv = 1.0f / Ss;
    char* Ob = smem;
    int qloc = wave * 32 + q;
    #pragma unroll
    for (int j = 0; j < 4; ++j) {
        u32 wa, wb;
        float va0 = o0[j * 4 + 0] * inv, va1 = o0[j * 4 + 1] * inv;
        float va2 = o0[j * 4 + 2] * inv, va3 = o0[j * 4 + 3] * inv;
        PKS(wa, va0, va1); PKS(wb, va2, va3);
        int d0 = 8 * j + 4 * hi;
        *(uint2*)(Ob + qloc * 128 + ((d0 * 2) ^ ((qloc & 7) << 4))) = make_uint2(wa, wb);
    }
    #pragma unroll
    for (int j = 0; j < 4; ++j) {
        u32 wa, wb;
        float va0 = o1[j * 4 + 0] * inv, va1 = o1[j * 4 + 1] * inv;
        float va2 = o1[j * 4 + 2] * inv, va3 = o1[j * 4 + 3] * inv;
        PKS(wa, va0, va1); PKS(wb, va2, va3);
        int d0 = 32 + 8 * j + 4 * hi;
        *(uint2*)(Ob + qloc * 128 + ((d0 * 2) ^ ((qloc & 7) << 4))) = make_uint2(wa, wb);
    }
    __syncthreads();
    long gb = (long)(b * 1024 + qt * 256) * 512 + h * 64;
    #pragma unroll
    for (int p = 0; p < 4; ++p) {
        int qr = p * 64 + (tid >> 3);
        int ss = tid & 7;
        u32x4 vv = *(const u32x4*)(Ob + qr * 128 + ((ss * 16) ^ ((qr & 7) << 4)));
        *(u32x4*)((char*)AO + (gb + (long)qr * 512 + ss * 8) * 2) = vv;
    }
}

// ---------------- launch ----------------

extern "C" void kernel_launch(void* const* d_in, const int* in_sizes, int n_in,
                              void* d_out, int out_size, void* d_ws, size_t ws_size,
                              hipStream_t stream) {
    const float* x    = (const float*)d_in[0];
    const int*   mask = (const int*)d_in[1];
    const float* Wqkv = (const float*)d_in[2];
    const float* W1   = (const float*)d_in[3];
    const float* b1   = (const float*)d_in[4];
    const float* W2   = (const float*)d_in[5];
    const float* Wout = (const float*)d_in[6];
    float* out = (float*)d_out;
    char* ws = (char*)d_ws;

    unsigned short* wqkvT = (unsigned short*)(ws + 16777216);  // 1.5 MB [1536][512]
    unsigned short* woutT = (unsigned short*)(ws + 18350080);  // 0.5 MB [512][512]
    unsigned short* Qb    = (unsigned short*)(ws + 18874368);  // 16 MB [bh][l][d]
    unsigned short* Kb    = (unsigned short*)(ws + 35651584);  // 16 MB fragment-linear
    unsigned short* VTb   = (unsigned short*)(ws + 52428800);  // 16 MB fragment-linear
    unsigned short* AOb   = (unsigned short*)(ws + 69206016);  // 16 MB [16384][512]
    float* btab           = (float*)(ws + 85983232);           // 128 KB (tail region)
    if (ws_size < 86114304) return;

    k_prepw<<<3072, 256, 0, stream>>>(Wqkv, wqkvT, Wout, woutT, W1, b1, W2, btab);
    k_gemm<0><<<dim3(12, 128), 256, 0, stream>>>(x, nullptr, wqkvT, 16384, 1536, Qb, Kb, VTb, nullptr);
    k_attn<<<512, 512, 0, stream>>>(Qb, Kb, VTb, mask, btab, AOb);
    k_gemm<1><<<dim3(4, 128), 256, 0, stream>>>(nullptr, AOb, woutT, 16384, 512, nullptr, nullptr, nullptr, out);
}

// Round 24
// 141.459 us; speedup vs baseline: 1.0522x; 1.0522x over previous
//
#include <hip/hip_runtime.h>
#include <hip/hip_bf16.h>

typedef short s16x8 __attribute__((ext_vector_type(8)));
typedef float f32x4 __attribute__((ext_vector_type(4)));
typedef float f32x16 __attribute__((ext_vector_type(16)));
typedef unsigned int u32;
typedef unsigned int u32x4 __attribute__((ext_vector_type(4)));
typedef unsigned short u16x4 __attribute__((ext_vector_type(4)));
typedef unsigned long long u64;

#define LOG2E 1.4426950408889634f
#define QSCALE 0.18033688011112042f  // 0.125 * log2(e)
#define NEG_BIG -3.0e38f

#define PKS(dst, a, b) asm("v_cvt_pk_bf16_f32 %0, %1, %2" : "=v"(dst) : "v"(a), "v"(b))
#define SWP(x, y) asm("v_permlane32_swap_b32 %0, %1" : "+v"(x), "+v"(y))

__device__ __forceinline__ unsigned short f2b(float f) {
    unsigned int u = __float_as_uint(f);
    unsigned int r = (u + 0x7fffu + ((u >> 16) & 1u)) >> 16;
    return (unsigned short)r;
}

__device__ __forceinline__ void g2l16(const void* g, void* l) {
    __builtin_amdgcn_global_load_lds(
        (const __attribute__((address_space(1))) unsigned int*)(g),
        (__attribute__((address_space(3))) unsigned int*)(l), 16, 0, 0);
}

// ---------------- weight prep: Wqkv^T, Wout^T, bias table ----------------
// r22: bias table pre-shifted by -8 (fixed softmax reference; no running max).
__global__ __launch_bounds__(256) void k_prepw(const float* __restrict__ Wqkv,
                                               unsigned short* __restrict__ wqkvT,
                                               const float* __restrict__ Wout,
                                               unsigned short* __restrict__ woutT,
                                               const float* __restrict__ W1,
                                               const float* __restrict__ b1,
                                               const float* __restrict__ W2,
                                               float* __restrict__ btab) {
    int bid = blockIdx.x, tid = threadIdx.x;
    {
        int idx = bid * 256 + tid;           // 786432 elements
        int k = idx & 511, n = idx >> 9;
        wqkvT[idx] = f2b(Wqkv[(long)k * 1536 + n]);
    }
    if (bid < 1024) {
        int idx = bid * 256 + tid;           // 262144 elements
        int k = idx & 511, n = idx >> 9;
        woutT[idx] = f2b(Wout[(long)k * 512 + n]);
    }
    if (bid >= 3064) {
        int idx = (bid - 3064) * 256 + tid;  // 0..2047
        if (idx <= 2045) {
            float t = 0.0f;
            if (idx != 2045) {
                float r = (float)(idx - 1022) * (8.0f / 1022.0f);
                float sg = (r > 0.f) ? 1.0f : ((r < 0.f) ? -1.0f : 0.0f);
                t = sg * log2f(fabsf(r) + 1.0f) * 0.3154648767971406f;  // 1/log2(9)
            }
            float acc[8] = {0, 0, 0, 0, 0, 0, 0, 0};
            float accc[8] = {0, 0, 0, 0, 0, 0, 0, 0};
            for (int j = 0; j < 64; ++j) {
                float hj = t * W1[j] + b1[j];
                hj = (hj > 0.f) ? hj : 0.2f * hj;
                float hc = b1[j];
                hc = (hc > 0.f) ? hc : 0.2f * hc;
                #pragma unroll
                for (int h = 0; h < 8; ++h) {
                    acc[h] += hj * W2[j * 8 + h];
                    accc[h] += hc * W2[j * 8 + h];
                }
            }
            #pragma unroll
            for (int h = 0; h < 8; ++h) {
                btab[h * 4096 + idx] = acc[h] * LOG2E - 8.0f;
                btab[h * 4096 + 2048 + idx] = accc[h] * LOG2E - 8.0f;
            }
        }
    }
}

// ---------------- GEMM: C = A @ BT^T, bf16 MFMA ----------------
template <int MODE>
__global__ __launch_bounds__(256) void k_gemm(const float* __restrict__ Af,
                                              const unsigned short* __restrict__ A16,
                                              const unsigned short* __restrict__ BT,
                                              int M, int N,
                                              unsigned short* __restrict__ Qp,
                                              unsigned short* __restrict__ Kp,
                                              unsigned short* __restrict__ VTp,
                                              float* __restrict__ Cout) {
    __shared__ __align__(16) unsigned short As[2][128 * 32];
    __shared__ __align__(16) unsigned short Bs[2][128 * 32];
    constexpr int NX = (MODE == 0) ? 12 : 4;      // N/128
    constexpr int NWG = (MODE == 0) ? 1536 : 512; // total workgroups (div by 8)
    int lid = blockIdx.y * NX + blockIdx.x;       // linear dispatch index (x fastest)
    int tile = (lid & 7) * (NWG >> 3) + (lid >> 3);
    int m0 = (tile / NX) * 128, n0 = (tile % NX) * 128;
    int tid = threadIdx.x;
    int wave = tid >> 6, lane = tid & 63, lr = lane & 15, g = lane >> 4;
    int wr = wave >> 1, wc = wave & 1;
    f32x4 acc[4][4] = {};
    const float* Af0 = Af + (long)(m0 + (tid >> 2)) * 512 + (tid & 3) * 8;
    const float* Af1 = Af0 + 64 * 512;
    const char* Ab = (const char*)A16 + (long)(m0 + (tid >> 2)) * 1024 + (tid & 3) * 16;
    const char* Bb = (const char*)BT + (long)(n0 + (tid >> 2)) * 1024 + (tid & 3) * 16;

    // prologue: stage tile 0 into buffer 0
    if (MODE == 0) {
        f32x4 a0 = *(const f32x4*)(Af0);
        f32x4 a1 = *(const f32x4*)(Af0 + 4);
        f32x4 a2 = *(const f32x4*)(Af1);
        f32x4 a3 = *(const f32x4*)(Af1 + 4);
        u32 w0, w1, w2, w3;
        PKS(w0, a0.x, a0.y); PKS(w1, a0.z, a0.w);
        PKS(w2, a1.x, a1.y); PKS(w3, a1.z, a1.w);
        *(u32x4*)((char*)As[0] + tid * 16) = u32x4{w0, w1, w2, w3};
        PKS(w0, a2.x, a2.y); PKS(w1, a2.z, a2.w);
        PKS(w2, a3.x, a3.y); PKS(w3, a3.z, a3.w);
        *(u32x4*)((char*)As[0] + 4096 + tid * 16) = u32x4{w0, w1, w2, w3};
    } else {
        g2l16(Ab, (char*)As[0] + wave * 1024);
        g2l16(Ab + 65536, (char*)As[0] + 4096 + wave * 1024);
    }
    g2l16(Bb, (char*)Bs[0] + wave * 1024);
    g2l16(Bb + 65536, (char*)Bs[0] + 4096 + wave * 1024);
    __syncthreads();

    for (int kt = 0; kt < 16; ++kt) {
        int cur = kt & 1;
        int nxt = cur ^ 1;
        f32x4 na0, na1, na2, na3;
        if (kt < 15) {
            if (MODE == 0) {
                na0 = *(const f32x4*)(Af0 + (kt + 1) * 32);
                na1 = *(const f32x4*)(Af0 + (kt + 1) * 32 + 4);
                na2 = *(const f32x4*)(Af1 + (kt + 1) * 32);
                na3 = *(const f32x4*)(Af1 + (kt + 1) * 32 + 4);
            } else {
                g2l16(Ab + (kt + 1) * 64, (char*)As[nxt] + wave * 1024);
                g2l16(Ab + 65536 + (kt + 1) * 64, (char*)As[nxt] + 4096 + wave * 1024);
            }
            g2l16(Bb + (kt + 1) * 64, (char*)Bs[nxt] + wave * 1024);
            g2l16(Bb + 65536 + (kt + 1) * 64, (char*)Bs[nxt] + 4096 + wave * 1024);
        }
        s16x8 av[4], bv[4];
        #pragma unroll
        for (int f = 0; f < 4; ++f) {
            av[f] = *(const s16x8*)((char*)As[cur] + (wr * 64 + f * 16 + lr) * 64 + g * 16);
            bv[f] = *(const s16x8*)((char*)Bs[cur] + (wc * 64 + f * 16 + lr) * 64 + g * 16);
        }
        __builtin_amdgcn_s_setprio(1);
        #pragma unroll
        for (int fi = 0; fi < 4; ++fi)
            #pragma unroll
            for (int fj = 0; fj < 4; ++fj)
                acc[fi][fj] = __builtin_amdgcn_mfma_f32_16x16x32_bf16(bv[fj], av[fi], acc[fi][fj], 0, 0, 0);
        __builtin_amdgcn_s_setprio(0);
        if (MODE == 0 && kt < 15) {
            u32 w0, w1, w2, w3;
            PKS(w0, na0.x, na0.y); PKS(w1, na0.z, na0.w);
            PKS(w2, na1.x, na1.y); PKS(w3, na1.z, na1.w);
            *(u32x4*)((char*)As[nxt] + tid * 16) = u32x4{w0, w1, w2, w3};
            PKS(w0, na2.x, na2.y); PKS(w1, na2.z, na2.w);
            PKS(w2, na3.x, na3.y); PKS(w3, na3.z, na3.w);
            *(u32x4*)((char*)As[nxt] + 4096 + tid * 16) = u32x4{w0, w1, w2, w3};
        }
        __syncthreads();
    }
    // epilogue (swapped layout): lane holds C[gm = m0+wr*64+fi*16+lr][n = n0+wc*64+fj*16+g*4+e]
    #pragma unroll
    for (int fi = 0; fi < 4; ++fi) {
        int gm = m0 + wr * 64 + fi * 16 + lr;
        if (MODE == 0) {
            int bq = gm >> 10, lp = gm & 1023;
            int kvt = lp >> 6, kvl = lp & 63;
            #pragma unroll
            for (int fj = 0; fj < 4; ++fj) {
                int col0 = n0 + wc * 64 + fj * 16 + g * 4;  // 4-aligned; sec/h constant over e
                int sec = col0 >> 9, c0 = col0 & 511, h = c0 >> 6, dd0 = c0 & 63;
                int bh = bq * 8 + h;
                float v0 = acc[fi][fj][0], v1 = acc[fi][fj][1];
                float v2 = acc[fi][fj][2], v3 = acc[fi][fj][3];
                if (sec == 0) {
                    u32 w0, w1;
                    float q0 = v0 * QSCALE, q1 = v1 * QSCALE, q2 = v2 * QSCALE, q3 = v3 * QSCALE;
                    PKS(w0, q0, q1); PKS(w1, q2, q3);
                    *(uint2*)(Qp + (long)(bh * 1024 + lp) * 64 + dd0) = make_uint2(w0, w1);
                } else if (sec == 1) {
                    u32 w0, w1;
                    PKS(w0, v0, v1); PKS(w1, v2, v3);
                    long off = (long)bh * 65536 + kvt * 4096 + (kvl >> 5) * 2048 +
                               (dd0 >> 4) * 512 + ((((dd0 >> 3) & 1) << 5) + (kvl & 31)) * 8 + (dd0 & 7);
                    *(uint2*)(Kp + off) = make_uint2(w0, w1);
                } else {
                    // VT fragment-linear: consecutive dd -> stride 8 shorts
                    long off = (long)bh * 65536 + kvt * 4096 + (dd0 >> 5) * 2048 +
                               (kvl >> 4) * 512 + ((((kvl >> 3) & 1) << 5) + (dd0 & 31)) * 8 + (kvl & 7);
                    VTp[off] = f2b(v0);
                    VTp[off + 8] = f2b(v1);
                    VTp[off + 16] = f2b(v2);
                    VTp[off + 24] = f2b(v3);
                }
            }
        } else {
            #pragma unroll
            for (int fj = 0; fj < 4; ++fj) {
                int col0 = n0 + wc * 64 + fj * 16 + g * 4;
                *(f32x4*)(Cout + (long)gm * N + col0) = acc[fi][fj];
            }
        }
    }
}

// ---------------- flash attention ----------------
// r22 compute structure (immediate softmax, fixed reference) + r24: 4-slot ring,
// prefetch distance 2, barrier only after ODD iterations (8 drains instead of 16).
// Safety: stage(t+2)->slot (t+2)&3; exactly one barrier lies in (t, t+2) for any t
// (parity), which vmcnt-drains the stage before its read and orders the overwrite
// against slot readers from iter t-2 (two barriers back).
#define ATT_STAGE(MTT) do { \
    char* Kn_ = smem + ((MTT) & 3) * 16384; \
    g2l16(Kg + (MTT) * 8192 + tid * 16, Kn_ + wave * 1024); \
    g2l16(Vg + (MTT) * 8192 + tid * 16, Kn_ + 8192 + wave * 1024); \
  } while (0)

#define ATT_PV(VPTR) do { \
    __builtin_amdgcn_s_setprio(1); \
    o0 = __builtin_amdgcn_mfma_f32_32x32x16_bf16(*(const s16x8*)((VPTR) + lx), Pc0, o0, 0, 0, 0); \
    o0 = __builtin_amdgcn_mfma_f32_32x32x16_bf16(*(const s16x8*)((VPTR) + 1024 + lx), Pc1, o0, 0, 0, 0); \
    o0 = __builtin_amdgcn_mfma_f32_32x32x16_bf16(*(const s16x8*)((VPTR) + 2048 + lx), Pc2, o0, 0, 0, 0); \
    o0 = __builtin_amdgcn_mfma_f32_32x32x16_bf16(*(const s16x8*)((VPTR) + 3072 + lx), Pc3, o0, 0, 0, 0); \
    o1 = __builtin_amdgcn_mfma_f32_32x32x16_bf16(*(const s16x8*)((VPTR) + 4096 + lx), Pc0, o1, 0, 0, 0); \
    o1 = __builtin_amdgcn_mfma_f32_32x32x16_bf16(*(const s16x8*)((VPTR) + 5120 + lx), Pc1, o1, 0, 0, 0); \
    o1 = __builtin_amdgcn_mfma_f32_32x32x16_bf16(*(const s16x8*)((VPTR) + 6144 + lx), Pc2, o1, 0, 0, 0); \
    o1 = __builtin_amdgcn_mfma_f32_32x32x16_bf16(*(const s16x8*)((VPTR) + 7168 + lx), Pc3, o1, 0, 0, 0); \
    __builtin_amdgcn_s_setprio(0); \
  } while (0)

#define ATT_ITER(MT, BAR) do { \
    if ((MT) + 2 < 16) ATT_STAGE((MT) + 2); \
    char* Kl = smem + ((MT) & 3) * 16384; \
    int ib = (MT) * 64 - l + 1022; \
    float b0[16], b1v[16]; \
    { \
        const float* bq = bp + ib + 4 * hi; \
        _Pragma("unroll") \
        for (int k = 0; k < 4; ++k) { \
            f32x4 va = *(const f32x4*)(bq + 8 * k); \
            f32x4 vb = *(const f32x4*)(bq + 32 + 8 * k); \
            b0[4 * k + 0] = va.x; b0[4 * k + 1] = va.y; \
            b0[4 * k + 2] = va.z; b0[4 * k + 3] = va.w; \
            b1v[4 * k + 0] = vb.x; b1v[4 * k + 1] = vb.y; \
            b1v[4 * k + 2] = vb.z; b1v[4 * k + 3] = vb.w; \
        } \
    } \
    f32x16 s0 = {}, s1 = {}; \
    __builtin_amdgcn_s_setprio(1); \
    s0 = __builtin_amdgcn_mfma_f32_32x32x16_bf16(*(const s16x8*)(Kl + lx), qf0, s0, 0, 0, 0); \
    s0 = __builtin_amdgcn_mfma_f32_32x32x16_bf16(*(const s16x8*)(Kl + 1024 + lx), qf1, s0, 0, 0, 0); \
    s0 = __builtin_amdgcn_mfma_f32_32x32x16_bf16(*(const s16x8*)(Kl + 2048 + lx), qf2, s0, 0, 0, 0); \
    s0 = __builtin_amdgcn_mfma_f32_32x32x16_bf16(*(const s16x8*)(Kl + 3072 + lx), qf3, s0, 0, 0, 0); \
    s1 = __builtin_amdgcn_mfma_f32_32x32x16_bf16(*(const s16x8*)(Kl + 4096 + lx), qf0, s1, 0, 0, 0); \
    s1 = __builtin_amdgcn_mfma_f32_32x32x16_bf16(*(const s16x8*)(Kl + 5120 + lx), qf1, s1, 0, 0, 0); \
    s1 = __builtin_amdgcn_mfma_f32_32x32x16_bf16(*(const s16x8*)(Kl + 6144 + lx), qf2, s1, 0, 0, 0); \
    s1 = __builtin_amdgcn_mfma_f32_32x32x16_bf16(*(const s16x8*)(Kl + 7168 + lx), qf3, s1, 0, 0, 0); \
    __builtin_amdgcn_s_setprio(0); \
    u64 mb = *(const u64*)(smem + 65536 + (MT) * 8); \
    u32 wm0 = (u32)(mb >> (4 * hi)); \
    u32 wm1 = (u32)(mb >> (32 + 4 * hi)); \
    if ((MT) == 0 && hi == 0) b0[0] = c2; \
    _Pragma("unroll") \
    for (int r = 0; r < 16; ++r) { \
        int pos = (r & 3) + 8 * (r >> 2); \
        s0[r] = ((wm0 >> pos) & 1) ? s0[r] + b0[r] : NEG_BIG; \
        s1[r] = ((wm1 >> pos) & 1) ? s1[r] + b1v[r] : NEG_BIG; \
    } \
    _Pragma("unroll") \
    for (int r = 0; r < 16; ++r) s0[r] = __builtin_amdgcn_exp2f(s0[r]); \
    _Pragma("unroll") \
    for (int r = 0; r < 16; ++r) s1[r] = __builtin_amdgcn_exp2f(s1[r]); \
    { \
        float u0 = s0[0] + s0[1], u1 = s0[2] + s0[3], u2 = s0[4] + s0[5], u3 = s0[6] + s0[7]; \
        float u4 = s0[8] + s0[9], u5 = s0[10] + s0[11], u6 = s0[12] + s0[13], u7 = s0[14] + s0[15]; \
        float v0 = s1[0] + s1[1], v1 = s1[2] + s1[3], v2 = s1[4] + s1[5], v3 = s1[6] + s1[7]; \
        float v4 = s1[8] + s1[9], v5 = s1[10] + s1[11], v6 = s1[12] + s1[13], v7 = s1[14] + s1[15]; \
        u0 += u1; u2 += u3; u4 += u5; u6 += u7; \
        v0 += v1; v2 += v3; v4 += v5; v6 += v7; \
        u0 += u2; u4 += u6; v0 += v2; v4 += v6; \
        float ts = (u0 + u4) + (v0 + v4); \
        ts += __shfl_xor(ts, 32); \
        Ss += ts; \
    } \
    { \
        u32 x, y, x2, y2; \
        union { u32 w[4]; s16x8 v; } pt; \
        PKS(x, s0[0], s0[1]);  PKS(y, s0[4], s0[5]);  SWP(x, y); \
        PKS(x2, s0[2], s0[3]); PKS(y2, s0[6], s0[7]); SWP(x2, y2); \
        pt.w[0] = x; pt.w[1] = x2; pt.w[2] = y; pt.w[3] = y2; Pc0 = pt.v; \
        PKS(x, s0[8], s0[9]);   PKS(y, s0[12], s0[13]);  SWP(x, y); \
        PKS(x2, s0[10], s0[11]); PKS(y2, s0[14], s0[15]); SWP(x2, y2); \
        pt.w[0] = x; pt.w[1] = x2; pt.w[2] = y; pt.w[3] = y2; Pc1 = pt.v; \
        PKS(x, s1[0], s1[1]);  PKS(y, s1[4], s1[5]);  SWP(x, y); \
        PKS(x2, s1[2], s1[3]); PKS(y2, s1[6], s1[7]); SWP(x2, y2); \
        pt.w[0] = x; pt.w[1] = x2; pt.w[2] = y; pt.w[3] = y2; Pc2 = pt.v; \
        PKS(x, s1[8], s1[9]);   PKS(y, s1[12], s1[13]);  SWP(x, y); \
        PKS(x2, s1[10], s1[11]); PKS(y2, s1[14], s1[15]); SWP(x2, y2); \
        pt.w[0] = x; pt.w[1] = x2; pt.w[2] = y; pt.w[3] = y2; Pc3 = pt.v; \
    } \
    { \
        char* Vp_ = smem + ((MT) & 3) * 16384 + 8192; \
        ATT_PV(Vp_); \
    } \
    if (BAR) __syncthreads(); \
  } while (0)

__global__ __launch_bounds__(512, 2) void k_attn(const unsigned short* __restrict__ Q,
                                                 const unsigned short* __restrict__ Kb,
                                                 const unsigned short* __restrict__ VT,
                                                 const int* __restrict__ mask,
                                                 const float* __restrict__ btab,
                                                 unsigned short* __restrict__ AO) {
    __shared__ __align__(16) char smem[65664];  // 4x16K ring + mask @65536 (cap=2/CU via LDS)
    int lid = blockIdx.x;
    int wg = (lid & 7) * 64 + (lid >> 3);   // bijective XCD swizzle (512 = 8*64)
    int qt = wg & 3, bh = wg >> 2;
    int b = bh >> 3, h = bh & 7;
    int tid = threadIdx.x;
    int wave = tid >> 6, lane = tid & 63;
    int q = lane & 31, hi = lane >> 5;
    int l = qt * 256 + wave * 32 + q;
    const float* bt = btab + h * 4096;
    float c2 = bt[2045];
    const float* bp = bt + ((l == 0) ? 2048 : 0);

    const char* Kg = (const char*)Kb + (long)bh * 131072;
    const char* Vg = (const char*)VT + (long)bh * 131072;

    // mask bitmasks -> LDS (one u64 per 64-kv tile)
    if (tid < 16) {
        const int* mrow = mask + b * 1023;
        u64 bits = 0;
        for (int j = 0; j < 64; ++j) {
            int kv = tid * 64 + j;
            int bit = (kv == 0) ? 1 : (mrow[kv - 1] != 0);
            bits |= (u64)bit << j;
        }
        *(u64*)(smem + 65536 + tid * 8) = bits;
    }

    // Q fragments (B-operand): col=q, k = d = ko*16 + hi*8 + e
    const char* Qrow = (const char*)Q + ((long)bh * 1024 + l) * 128;
    s16x8 qf0 = *(const s16x8*)(Qrow + 0 * 32 + hi * 16);
    s16x8 qf1 = *(const s16x8*)(Qrow + 1 * 32 + hi * 16);
    s16x8 qf2 = *(const s16x8*)(Qrow + 2 * 32 + hi * 16);
    s16x8 qf3 = *(const s16x8*)(Qrow + 3 * 32 + hi * 16);

    f32x16 o0 = {}, o1 = {};
    float Ss = 0.f;
    int lx = lane * 16;
    s16x8 Pc0 = {}, Pc1 = {}, Pc2 = {}, Pc3 = {};  // carried P (plain VGPR vectors)

    // prologue: stage tiles 0,1 (ring slots 0,1)
    ATT_STAGE(0);
    ATT_STAGE(1);
    __syncthreads();

    ATT_ITER(0, 0);  ATT_ITER(1, 1);  ATT_ITER(2, 0);  ATT_ITER(3, 1);
    ATT_ITER(4, 0);  ATT_ITER(5, 1);  ATT_ITER(6, 0);  ATT_ITER(7, 1);
    ATT_ITER(8, 0);  ATT_ITER(9, 1);  ATT_ITER(10, 0); ATT_ITER(11, 1);
    ATT_ITER(12, 0); ATT_ITER(13, 1); ATT_ITER(14, 0); ATT_ITER(15, 1);

    // epilogue: normalize, transpose via LDS, coalesced store
    // (barrier after iter 15 already ordered all ring reads vs the reuse below)
    float inv = 1.0f / Ss;
    char* Ob = smem;
    int qloc = wave * 32 + q;
    #pragma unroll
    for (int j = 0; j < 4; ++j) {
        u32 wa, wb;
        float va0 = o0[j * 4 + 0] * inv, va1 = o0[j * 4 + 1] * inv;
        float va2 = o0[j * 4 + 2] * inv, va3 = o0[j * 4 + 3] * inv;
        PKS(wa, va0, va1); PKS(wb, va2, va3);
        int d0 = 8 * j + 4 * hi;
        *(uint2*)(Ob + qloc * 128 + ((d0 * 2) ^ ((qloc & 7) << 4))) = make_uint2(wa, wb);
    }
    #pragma unroll
    for (int j = 0; j < 4; ++j) {
        u32 wa, wb;
        float va0 = o1[j * 4 + 0] * inv, va1 = o1[j * 4 + 1] * inv;
        float va2 = o1[j * 4 + 2] * inv, va3 = o1[j * 4 + 3] * inv;
        PKS(wa, va0, va1); PKS(wb, va2, va3);
        int d0 = 32 + 8 * j + 4 * hi;
        *(uint2*)(Ob + qloc * 128 + ((d0 * 2) ^ ((qloc & 7) << 4))) = make_uint2(wa, wb);
    }
    __syncthreads();
    long gb = (long)(b * 1024 + qt * 256) * 512 + h * 64;
    #pragma unroll
    for (int p = 0; p < 4; ++p) {
        int qr = p * 64 + (tid >> 3);
        int ss = tid & 7;
        u32x4 vv = *(const u32x4*)(Ob + qr * 128 + ((ss * 16) ^ ((qr & 7) << 4)));
        *(u32x4*)((char*)AO + (gb + (long)qr * 512 + ss * 8) * 2) = vv;
    }
}

// ---------------- launch ----------------

extern "C" void kernel_launch(void* const* d_in, const int* in_sizes, int n_in,
                              void* d_out, int out_size, void* d_ws, size_t ws_size,
                              hipStream_t stream) {
    const float* x    = (const float*)d_in[0];
    const int*   mask = (const int*)d_in[1];
    const float* Wqkv = (const float*)d_in[2];
    const float* W1   = (const float*)d_in[3];
    const float* b1   = (const float*)d_in[4];
    const float* W2   = (const float*)d_in[5];
    const float* Wout = (const float*)d_in[6];
    float* out = (float*)d_out;
    char* ws = (char*)d_ws;

    unsigned short* wqkvT = (unsigned short*)(ws + 16777216);  // 1.5 MB [1536][512]
    unsigned short* woutT = (unsigned short*)(ws + 18350080);  // 0.5 MB [512][512]
    unsigned short* Qb    = (unsigned short*)(ws + 18874368);  // 16 MB [bh][l][d]
    unsigned short* Kb    = (unsigned short*)(ws + 35651584);  // 16 MB fragment-linear
    unsigned short* VTb   = (unsigned short*)(ws + 52428800);  // 16 MB fragment-linear
    unsigned short* AOb   = (unsigned short*)(ws + 69206016);  // 16 MB [16384][512]
    float* btab           = (float*)(ws + 85983232);           // 128 KB (tail region)
    if (ws_size < 86114304) return;

    k_prepw<<<3072, 256, 0, stream>>>(Wqkv, wqkvT, Wout, woutT, W1, b1, W2, btab);
    k_gemm<0><<<dim3(12, 128), 256, 0, stream>>>(x, nullptr, wqkvT, 16384, 1536, Qb, Kb, VTb, nullptr);
    k_attn<<<512, 512, 0, stream>>>(Qb, Kb, VTb, mask, btab, AOb);
    k_gemm<1><<<dim3(4, 128), 256, 0, stream>>>(nullptr, AOb, woutT, 16384, 512, nullptr, nullptr, nullptr, out);
}

// Round 25
// 141.190 us; speedup vs baseline: 1.0542x; 1.0019x over previous
//
#include <hip/hip_runtime.h>
#include <hip/hip_bf16.h>

typedef short s16x8 __attribute__((ext_vector_type(8)));
typedef float f32x4 __attribute__((ext_vector_type(4)));
typedef float f32x16 __attribute__((ext_vector_type(16)));
typedef unsigned int u32;
typedef unsigned int u32x4 __attribute__((ext_vector_type(4)));
typedef unsigned short u16x4 __attribute__((ext_vector_type(4)));
typedef unsigned long long u64;

#define LOG2E 1.4426950408889634f
#define QSCALE 0.18033688011112042f  // 0.125 * log2(e)
#define NEG_BIG -3.0e38f

#define PKS(dst, a, b) asm("v_cvt_pk_bf16_f32 %0, %1, %2" : "=v"(dst) : "v"(a), "v"(b))
#define SWP(x, y) asm("v_permlane32_swap_b32 %0, %1" : "+v"(x), "+v"(y))

__device__ __forceinline__ unsigned short f2b(float f) {
    unsigned int u = __float_as_uint(f);
    unsigned int r = (u + 0x7fffu + ((u >> 16) & 1u)) >> 16;
    return (unsigned short)r;
}

__device__ __forceinline__ void g2l16(const void* g, void* l) {
    __builtin_amdgcn_global_load_lds(
        (const __attribute__((address_space(1))) unsigned int*)(g),
        (__attribute__((address_space(3))) unsigned int*)(l), 16, 0, 0);
}

// ---------------- weight prep: Wqkv^T, Wout^T, bias table ----------------
// r22: bias table pre-shifted by -8 (fixed softmax reference; no running max).
__global__ __launch_bounds__(256) void k_prepw(const float* __restrict__ Wqkv,
                                               unsigned short* __restrict__ wqkvT,
                                               const float* __restrict__ Wout,
                                               unsigned short* __restrict__ woutT,
                                               const float* __restrict__ W1,
                                               const float* __restrict__ b1,
                                               const float* __restrict__ W2,
                                               float* __restrict__ btab) {
    int bid = blockIdx.x, tid = threadIdx.x;
    {
        int idx = bid * 256 + tid;           // 786432 elements
        int k = idx & 511, n = idx >> 9;
        wqkvT[idx] = f2b(Wqkv[(long)k * 1536 + n]);
    }
    if (bid < 1024) {
        int idx = bid * 256 + tid;           // 262144 elements
        int k = idx & 511, n = idx >> 9;
        woutT[idx] = f2b(Wout[(long)k * 512 + n]);
    }
    if (bid >= 3064) {
        int idx = (bid - 3064) * 256 + tid;  // 0..2047
        if (idx <= 2045) {
            float t = 0.0f;
            if (idx != 2045) {
                float r = (float)(idx - 1022) * (8.0f / 1022.0f);
                float sg = (r > 0.f) ? 1.0f : ((r < 0.f) ? -1.0f : 0.0f);
                t = sg * log2f(fabsf(r) + 1.0f) * 0.3154648767971406f;  // 1/log2(9)
            }
            float acc[8] = {0, 0, 0, 0, 0, 0, 0, 0};
            float accc[8] = {0, 0, 0, 0, 0, 0, 0, 0};
            for (int j = 0; j < 64; ++j) {
                float hj = t * W1[j] + b1[j];
                hj = (hj > 0.f) ? hj : 0.2f * hj;
                float hc = b1[j];
                hc = (hc > 0.f) ? hc : 0.2f * hc;
                #pragma unroll
                for (int h = 0; h < 8; ++h) {
                    acc[h] += hj * W2[j * 8 + h];
                    accc[h] += hc * W2[j * 8 + h];
                }
            }
            #pragma unroll
            for (int h = 0; h < 8; ++h) {
                btab[h * 4096 + idx] = acc[h] * LOG2E - 8.0f;
                btab[h * 4096 + 2048 + idx] = accc[h] * LOG2E - 8.0f;
            }
        }
    }
}

// ---------------- GEMM: C = A @ BT^T, bf16 MFMA ----------------
template <int MODE>
__global__ __launch_bounds__(256) void k_gemm(const float* __restrict__ Af,
                                              const unsigned short* __restrict__ A16,
                                              const unsigned short* __restrict__ BT,
                                              int M, int N,
                                              unsigned short* __restrict__ Qp,
                                              unsigned short* __restrict__ Kp,
                                              unsigned short* __restrict__ VTp,
                                              float* __restrict__ Cout) {
    __shared__ __align__(16) unsigned short As[2][128 * 32];
    __shared__ __align__(16) unsigned short Bs[2][128 * 32];
    constexpr int NX = (MODE == 0) ? 12 : 4;      // N/128
    constexpr int NWG = (MODE == 0) ? 1536 : 512; // total workgroups (div by 8)
    int lid = blockIdx.y * NX + blockIdx.x;       // linear dispatch index (x fastest)
    int tile = (lid & 7) * (NWG >> 3) + (lid >> 3);
    int m0 = (tile / NX) * 128, n0 = (tile % NX) * 128;
    int tid = threadIdx.x;
    int wave = tid >> 6, lane = tid & 63, lr = lane & 15, g = lane >> 4;
    int wr = wave >> 1, wc = wave & 1;
    f32x4 acc[4][4] = {};
    const float* Af0 = Af + (long)(m0 + (tid >> 2)) * 512 + (tid & 3) * 8;
    const float* Af1 = Af0 + 64 * 512;
    const char* Ab = (const char*)A16 + (long)(m0 + (tid >> 2)) * 1024 + (tid & 3) * 16;
    const char* Bb = (const char*)BT + (long)(n0 + (tid >> 2)) * 1024 + (tid & 3) * 16;

    // prologue: stage tile 0 into buffer 0
    if (MODE == 0) {
        f32x4 a0 = *(const f32x4*)(Af0);
        f32x4 a1 = *(const f32x4*)(Af0 + 4);
        f32x4 a2 = *(const f32x4*)(Af1);
        f32x4 a3 = *(const f32x4*)(Af1 + 4);
        u32 w0, w1, w2, w3;
        PKS(w0, a0.x, a0.y); PKS(w1, a0.z, a0.w);
        PKS(w2, a1.x, a1.y); PKS(w3, a1.z, a1.w);
        *(u32x4*)((char*)As[0] + tid * 16) = u32x4{w0, w1, w2, w3};
        PKS(w0, a2.x, a2.y); PKS(w1, a2.z, a2.w);
        PKS(w2, a3.x, a3.y); PKS(w3, a3.z, a3.w);
        *(u32x4*)((char*)As[0] + 4096 + tid * 16) = u32x4{w0, w1, w2, w3};
    } else {
        g2l16(Ab, (char*)As[0] + wave * 1024);
        g2l16(Ab + 65536, (char*)As[0] + 4096 + wave * 1024);
    }
    g2l16(Bb, (char*)Bs[0] + wave * 1024);
    g2l16(Bb + 65536, (char*)Bs[0] + 4096 + wave * 1024);
    __syncthreads();

    for (int kt = 0; kt < 16; ++kt) {
        int cur = kt & 1;
        int nxt = cur ^ 1;
        f32x4 na0, na1, na2, na3;
        if (kt < 15) {
            if (MODE == 0) {
                na0 = *(const f32x4*)(Af0 + (kt + 1) * 32);
                na1 = *(const f32x4*)(Af0 + (kt + 1) * 32 + 4);
                na2 = *(const f32x4*)(Af1 + (kt + 1) * 32);
                na3 = *(const f32x4*)(Af1 + (kt + 1) * 32 + 4);
            } else {
                g2l16(Ab + (kt + 1) * 64, (char*)As[nxt] + wave * 1024);
                g2l16(Ab + 65536 + (kt + 1) * 64, (char*)As[nxt] + 4096 + wave * 1024);
            }
            g2l16(Bb + (kt + 1) * 64, (char*)Bs[nxt] + wave * 1024);
            g2l16(Bb + 65536 + (kt + 1) * 64, (char*)Bs[nxt] + 4096 + wave * 1024);
        }
        s16x8 av[4], bv[4];
        #pragma unroll
        for (int f = 0; f < 4; ++f) {
            av[f] = *(const s16x8*)((char*)As[cur] + (wr * 64 + f * 16 + lr) * 64 + g * 16);
            bv[f] = *(const s16x8*)((char*)Bs[cur] + (wc * 64 + f * 16 + lr) * 64 + g * 16);
        }
        __builtin_amdgcn_s_setprio(1);
        #pragma unroll
        for (int fi = 0; fi < 4; ++fi)
            #pragma unroll
            for (int fj = 0; fj < 4; ++fj)
                acc[fi][fj] = __builtin_amdgcn_mfma_f32_16x16x32_bf16(bv[fj], av[fi], acc[fi][fj], 0, 0, 0);
        __builtin_amdgcn_s_setprio(0);
        if (MODE == 0 && kt < 15) {
            u32 w0, w1, w2, w3;
            PKS(w0, na0.x, na0.y); PKS(w1, na0.z, na0.w);
            PKS(w2, na1.x, na1.y); PKS(w3, na1.z, na1.w);
            *(u32x4*)((char*)As[nxt] + tid * 16) = u32x4{w0, w1, w2, w3};
            PKS(w0, na2.x, na2.y); PKS(w1, na2.z, na2.w);
            PKS(w2, na3.x, na3.y); PKS(w3, na3.z, na3.w);
            *(u32x4*)((char*)As[nxt] + 4096 + tid * 16) = u32x4{w0, w1, w2, w3};
        }
        __syncthreads();
    }
    // epilogue (swapped layout): lane holds C[gm = m0+wr*64+fi*16+lr][n = n0+wc*64+fj*16+g*4+e]
    #pragma unroll
    for (int fi = 0; fi < 4; ++fi) {
        int gm = m0 + wr * 64 + fi * 16 + lr;
        if (MODE == 0) {
            int bq = gm >> 10, lp = gm & 1023;
            int kvt = lp >> 6, kvl = lp & 63;
            #pragma unroll
            for (int fj = 0; fj < 4; ++fj) {
                int col0 = n0 + wc * 64 + fj * 16 + g * 4;  // 4-aligned; sec/h constant over e
                int sec = col0 >> 9, c0 = col0 & 511, h = c0 >> 6, dd0 = c0 & 63;
                int bh = bq * 8 + h;
                float v0 = acc[fi][fj][0], v1 = acc[fi][fj][1];
                float v2 = acc[fi][fj][2], v3 = acc[fi][fj][3];
                if (sec == 0) {
                    u32 w0, w1;
                    float q0 = v0 * QSCALE, q1 = v1 * QSCALE, q2 = v2 * QSCALE, q3 = v3 * QSCALE;
                    PKS(w0, q0, q1); PKS(w1, q2, q3);
                    *(uint2*)(Qp + (long)(bh * 1024 + lp) * 64 + dd0) = make_uint2(w0, w1);
                } else if (sec == 1) {
                    u32 w0, w1;
                    PKS(w0, v0, v1); PKS(w1, v2, v3);
                    long off = (long)bh * 65536 + kvt * 4096 + (kvl >> 5) * 2048 +
                               (dd0 >> 4) * 512 + ((((dd0 >> 3) & 1) << 5) + (kvl & 31)) * 8 + (dd0 & 7);
                    *(uint2*)(Kp + off) = make_uint2(w0, w1);
                } else {
                    // VT fragment-linear: consecutive dd -> stride 8 shorts
                    long off = (long)bh * 65536 + kvt * 4096 + (dd0 >> 5) * 2048 +
                               (kvl >> 4) * 512 + ((((kvl >> 3) & 1) << 5) + (dd0 & 31)) * 8 + (kvl & 7);
                    VTp[off] = f2b(v0);
                    VTp[off + 8] = f2b(v1);
                    VTp[off + 16] = f2b(v2);
                    VTp[off + 24] = f2b(v3);
                }
            }
        } else {
            #pragma unroll
            for (int fj = 0; fj < 4; ++fj) {
                int col0 = n0 + wc * 64 + fj * 16 + g * 4;
                *(f32x4*)(Cout + (long)gm * N + col0) = acc[fi][fj];
            }
        }
    }
}

// ---------------- flash attention ----------------
// r24 frame (4-slot ring, barrier after odd iters, fixed-reference softmax)
// + r25: Ss computed on the matrix pipe — Sacc = mfma(ones, Pc_k, Sacc) gives
//   D[d][q] = sum_k P[k][q] in every row (k=16 spans both hi halves), so the
//   31-op VALU sum tree AND the shfl_xor(32) combine are deleted. Ss = Sacc[0].
#define ATT_STAGE(MTT) do { \
    char* Kn_ = smem + ((MTT) & 3) * 16384; \
    g2l16(Kg + (MTT) * 8192 + tid * 16, Kn_ + wave * 1024); \
    g2l16(Vg + (MTT) * 8192 + tid * 16, Kn_ + 8192 + wave * 1024); \
  } while (0)

#define ATT_PV(VPTR) do { \
    __builtin_amdgcn_s_setprio(1); \
    o0 = __builtin_amdgcn_mfma_f32_32x32x16_bf16(*(const s16x8*)((VPTR) + lx), Pc0, o0, 0, 0, 0); \
    o0 = __builtin_amdgcn_mfma_f32_32x32x16_bf16(*(const s16x8*)((VPTR) + 1024 + lx), Pc1, o0, 0, 0, 0); \
    o0 = __builtin_amdgcn_mfma_f32_32x32x16_bf16(*(const s16x8*)((VPTR) + 2048 + lx), Pc2, o0, 0, 0, 0); \
    o0 = __builtin_amdgcn_mfma_f32_32x32x16_bf16(*(const s16x8*)((VPTR) + 3072 + lx), Pc3, o0, 0, 0, 0); \
    o1 = __builtin_amdgcn_mfma_f32_32x32x16_bf16(*(const s16x8*)((VPTR) + 4096 + lx), Pc0, o1, 0, 0, 0); \
    o1 = __builtin_amdgcn_mfma_f32_32x32x16_bf16(*(const s16x8*)((VPTR) + 5120 + lx), Pc1, o1, 0, 0, 0); \
    o1 = __builtin_amdgcn_mfma_f32_32x32x16_bf16(*(const s16x8*)((VPTR) + 6144 + lx), Pc2, o1, 0, 0, 0); \
    o1 = __builtin_amdgcn_mfma_f32_32x32x16_bf16(*(const s16x8*)((VPTR) + 7168 + lx), Pc3, o1, 0, 0, 0); \
    Sacc = __builtin_amdgcn_mfma_f32_32x32x16_bf16(ones8, Pc0, Sacc, 0, 0, 0); \
    Sacc = __builtin_amdgcn_mfma_f32_32x32x16_bf16(ones8, Pc1, Sacc, 0, 0, 0); \
    Sacc = __builtin_amdgcn_mfma_f32_32x32x16_bf16(ones8, Pc2, Sacc, 0, 0, 0); \
    Sacc = __builtin_amdgcn_mfma_f32_32x32x16_bf16(ones8, Pc3, Sacc, 0, 0, 0); \
    __builtin_amdgcn_s_setprio(0); \
  } while (0)

#define ATT_ITER(MT, BAR) do { \
    if ((MT) + 2 < 16) ATT_STAGE((MT) + 2); \
    char* Kl = smem + ((MT) & 3) * 16384; \
    int ib = (MT) * 64 - l + 1022; \
    float b0[16], b1v[16]; \
    { \
        const float* bq = bp + ib + 4 * hi; \
        _Pragma("unroll") \
        for (int k = 0; k < 4; ++k) { \
            f32x4 va = *(const f32x4*)(bq + 8 * k); \
            f32x4 vb = *(const f32x4*)(bq + 32 + 8 * k); \
            b0[4 * k + 0] = va.x; b0[4 * k + 1] = va.y; \
            b0[4 * k + 2] = va.z; b0[4 * k + 3] = va.w; \
            b1v[4 * k + 0] = vb.x; b1v[4 * k + 1] = vb.y; \
            b1v[4 * k + 2] = vb.z; b1v[4 * k + 3] = vb.w; \
        } \
    } \
    f32x16 s0 = {}, s1 = {}; \
    __builtin_amdgcn_s_setprio(1); \
    s0 = __builtin_amdgcn_mfma_f32_32x32x16_bf16(*(const s16x8*)(Kl + lx), qf0, s0, 0, 0, 0); \
    s0 = __builtin_amdgcn_mfma_f32_32x32x16_bf16(*(const s16x8*)(Kl + 1024 + lx), qf1, s0, 0, 0, 0); \
    s0 = __builtin_amdgcn_mfma_f32_32x32x16_bf16(*(const s16x8*)(Kl + 2048 + lx), qf2, s0, 0, 0, 0); \
    s0 = __builtin_amdgcn_mfma_f32_32x32x16_bf16(*(const s16x8*)(Kl + 3072 + lx), qf3, s0, 0, 0, 0); \
    s1 = __builtin_amdgcn_mfma_f32_32x32x16_bf16(*(const s16x8*)(Kl + 4096 + lx), qf0, s1, 0, 0, 0); \
    s1 = __builtin_amdgcn_mfma_f32_32x32x16_bf16(*(const s16x8*)(Kl + 5120 + lx), qf1, s1, 0, 0, 0); \
    s1 = __builtin_amdgcn_mfma_f32_32x32x16_bf16(*(const s16x8*)(Kl + 6144 + lx), qf2, s1, 0, 0, 0); \
    s1 = __builtin_amdgcn_mfma_f32_32x32x16_bf16(*(const s16x8*)(Kl + 7168 + lx), qf3, s1, 0, 0, 0); \
    __builtin_amdgcn_s_setprio(0); \
    u64 mb = *(const u64*)(smem + 65536 + (MT) * 8); \
    u32 wm0 = (u32)(mb >> (4 * hi)); \
    u32 wm1 = (u32)(mb >> (32 + 4 * hi)); \
    if ((MT) == 0 && hi == 0) b0[0] = c2; \
    _Pragma("unroll") \
    for (int r = 0; r < 16; ++r) { \
        int pos = (r & 3) + 8 * (r >> 2); \
        s0[r] = ((wm0 >> pos) & 1) ? s0[r] + b0[r] : NEG_BIG; \
        s1[r] = ((wm1 >> pos) & 1) ? s1[r] + b1v[r] : NEG_BIG; \
    } \
    _Pragma("unroll") \
    for (int r = 0; r < 16; ++r) s0[r] = __builtin_amdgcn_exp2f(s0[r]); \
    _Pragma("unroll") \
    for (int r = 0; r < 16; ++r) s1[r] = __builtin_amdgcn_exp2f(s1[r]); \
    { \
        u32 x, y, x2, y2; \
        union { u32 w[4]; s16x8 v; } pt; \
        PKS(x, s0[0], s0[1]);  PKS(y, s0[4], s0[5]);  SWP(x, y); \
        PKS(x2, s0[2], s0[3]); PKS(y2, s0[6], s0[7]); SWP(x2, y2); \
        pt.w[0] = x; pt.w[1] = x2; pt.w[2] = y; pt.w[3] = y2; Pc0 = pt.v; \
        PKS(x, s0[8], s0[9]);   PKS(y, s0[12], s0[13]);  SWP(x, y); \
        PKS(x2, s0[10], s0[11]); PKS(y2, s0[14], s0[15]); SWP(x2, y2); \
        pt.w[0] = x; pt.w[1] = x2; pt.w[2] = y; pt.w[3] = y2; Pc1 = pt.v; \
        PKS(x, s1[0], s1[1]);  PKS(y, s1[4], s1[5]);  SWP(x, y); \
        PKS(x2, s1[2], s1[3]); PKS(y2, s1[6], s1[7]); SWP(x2, y2); \
        pt.w[0] = x; pt.w[1] = x2; pt.w[2] = y; pt.w[3] = y2; Pc2 = pt.v; \
        PKS(x, s1[8], s1[9]);   PKS(y, s1[12], s1[13]);  SWP(x, y); \
        PKS(x2, s1[10], s1[11]); PKS(y2, s1[14], s1[15]); SWP(x2, y2); \
        pt.w[0] = x; pt.w[1] = x2; pt.w[2] = y; pt.w[3] = y2; Pc3 = pt.v; \
    } \
    { \
        char* Vp_ = smem + ((MT) & 3) * 16384 + 8192; \
        ATT_PV(Vp_); \
    } \
    if (BAR) __syncthreads(); \
  } while (0)

__global__ __launch_bounds__(512, 2) void k_attn(const unsigned short* __restrict__ Q,
                                                 const unsigned short* __restrict__ Kb,
                                                 const unsigned short* __restrict__ VT,
                                                 const int* __restrict__ mask,
                                                 const float* __restrict__ btab,
                                                 unsigned short* __restrict__ AO) {
    __shared__ __align__(16) char smem[65664];  // 4x16K ring + mask @65536 (cap=2/CU via LDS)
    int lid = blockIdx.x;
    int wg = (lid & 7) * 64 + (lid >> 3);   // bijective XCD swizzle (512 = 8*64)
    int qt = wg & 3, bh = wg >> 2;
    int b = bh >> 3, h = bh & 7;
    int tid = threadIdx.x;
    int wave = tid >> 6, lane = tid & 63;
    int q = lane & 31, hi = lane >> 5;
    int l = qt * 256 + wave * 32 + q;
    const float* bt = btab + h * 4096;
    float c2 = bt[2045];
    const float* bp = bt + ((l == 0) ? 2048 : 0);

    const char* Kg = (const char*)Kb + (long)bh * 131072;
    const char* Vg = (const char*)VT + (long)bh * 131072;

    // mask bitmasks -> LDS (one u64 per 64-kv tile)
    if (tid < 16) {
        const int* mrow = mask + b * 1023;
        u64 bits = 0;
        for (int j = 0; j < 64; ++j) {
            int kv = tid * 64 + j;
            int bit = (kv == 0) ? 1 : (mrow[kv - 1] != 0);
            bits |= (u64)bit << j;
        }
        *(u64*)(smem + 65536 + tid * 8) = bits;
    }

    // Q fragments (B-operand): col=q, k = d = ko*16 + hi*8 + e
    const char* Qrow = (const char*)Q + ((long)bh * 1024 + l) * 128;
    s16x8 qf0 = *(const s16x8*)(Qrow + 0 * 32 + hi * 16);
    s16x8 qf1 = *(const s16x8*)(Qrow + 1 * 32 + hi * 16);
    s16x8 qf2 = *(const s16x8*)(Qrow + 2 * 32 + hi * 16);
    s16x8 qf3 = *(const s16x8*)(Qrow + 3 * 32 + hi * 16);

    f32x16 o0 = {}, o1 = {}, Sacc = {};
    int lx = lane * 16;
    s16x8 Pc0 = {}, Pc1 = {}, Pc2 = {}, Pc3 = {};  // carried P (plain VGPR vectors)
    s16x8 ones8;
    {
        union { u32 w[4]; s16x8 v; } ou;
        ou.w[0] = ou.w[1] = ou.w[2] = ou.w[3] = 0x3F803F80u;  // bf16 1.0 x8
        ones8 = ou.v;
    }

    // prologue: stage tiles 0,1 (ring slots 0,1)
    ATT_STAGE(0);
    ATT_STAGE(1);
    __syncthreads();

    ATT_ITER(0, 0);  ATT_ITER(1, 1);  ATT_ITER(2, 0);  ATT_ITER(3, 1);
    ATT_ITER(4, 0);  ATT_ITER(5, 1);  ATT_ITER(6, 0);  ATT_ITER(7, 1);
    ATT_ITER(8, 0);  ATT_ITER(9, 1);  ATT_ITER(10, 0); ATT_ITER(11, 1);
    ATT_ITER(12, 0); ATT_ITER(13, 1); ATT_ITER(14, 0); ATT_ITER(15, 1);

    // epilogue: normalize, transpose via LDS, coalesced store
    // (barrier after iter 15 already ordered all ring reads vs the reuse below)
    float Ss = Sacc[0];
    float inv = 1.0f / Ss;
    char* Ob = smem;
    int qloc = wave * 32 + q;
    #pragma unroll
    for (int j = 0; j < 4; ++j) {
        u32 wa, wb;
        float va0 = o0[j * 4 + 0] * inv, va1 = o0[j * 4 + 1] * inv;
        float va2 = o0[j * 4 + 2] * inv, va3 = o0[j * 4 + 3] * inv;
        PKS(wa, va0, va1); PKS(wb, va2, va3);
        int d0 = 8 * j + 4 * hi;
        *(uint2*)(Ob + qloc * 128 + ((d0 * 2) ^ ((qloc & 7) << 4))) = make_uint2(wa, wb);
    }
    #pragma unroll
    for (int j = 0; j < 4; ++j) {
        u32 wa, wb;
        float va0 = o1[j * 4 + 0] * inv, va1 = o1[j * 4 + 1] * inv;
        float va2 = o1[j * 4 + 2] * inv, va3 = o1[j * 4 + 3] * inv;
        PKS(wa, va0, va1); PKS(wb, va2, va3);
        int d0 = 32 + 8 * j + 4 * hi;
        *(uint2*)(Ob + qloc * 128 + ((d0 * 2) ^ ((qloc & 7) << 4))) = make_uint2(wa, wb);
    }
    __syncthreads();
    long gb = (long)(b * 1024 + qt * 256) * 512 + h * 64;
    #pragma unroll
    for (int p = 0; p < 4; ++p) {
        int qr = p * 64 + (tid >> 3);
        int ss = tid & 7;
        u32x4 vv = *(const u32x4*)(Ob + qr * 128 + ((ss * 16) ^ ((qr & 7) << 4)));
        *(u32x4*)((char*)AO + (gb + (long)qr * 512 + ss * 8) * 2) = vv;
    }
}

// ---------------- launch ----------------

extern "C" void kernel_launch(void* const* d_in, const int* in_sizes, int n_in,
                              void* d_out, int out_size, void* d_ws, size_t ws_size,
                              hipStream_t stream) {
    const float* x    = (const float*)d_in[0];
    const int*   mask = (const int*)d_in[1];
    const float* Wqkv = (const float*)d_in[2];
    const float* W1   = (const float*)d_in[3];
    const float* b1   = (const float*)d_in[4];
    const float* W2   = (const float*)d_in[5];
    const float* Wout = (const float*)d_in[6];
    float* out = (float*)d_out;
    char* ws = (char*)d_ws;

    unsigned short* wqkvT = (unsigned short*)(ws + 16777216);  // 1.5 MB [1536][512]
    unsigned short* woutT = (unsigned short*)(ws + 18350080);  // 0.5 MB [512][512]
    unsigned short* Qb    = (unsigned short*)(ws + 18874368);  // 16 MB [bh][l][d]
    unsigned short* Kb    = (unsigned short*)(ws + 35651584);  // 16 MB fragment-linear
    unsigned short* VTb   = (unsigned short*)(ws + 52428800);  // 16 MB fragment-linear
    unsigned short* AOb   = (unsigned short*)(ws + 69206016);  // 16 MB [16384][512]
    float* btab           = (float*)(ws + 85983232);           // 128 KB (tail region)
    if (ws_size < 86114304) return;

    k_prepw<<<3072, 256, 0, stream>>>(Wqkv, wqkvT, Wout, woutT, W1, b1, W2, btab);
    k_gemm<0><<<dim3(12, 128), 256, 0, stream>>>(x, nullptr, wqkvT, 16384, 1536, Qb, Kb, VTb, nullptr);
    k_attn<<<512, 512, 0, stream>>>(Qb, Kb, VTb, mask, btab, AOb);
    k_gemm<1><<<dim3(4, 128), 256, 0, stream>>>(nullptr, AOb, woutT, 16384, 512, nullptr, nullptr, nullptr, out);
}

// Round 26
// 140.394 us; speedup vs baseline: 1.0602x; 1.0057x over previous
//
#include <hip/hip_runtime.h>
#include <hip/hip_bf16.h>

typedef short s16x8 __attribute__((ext_vector_type(8)));
typedef float f32x4 __attribute__((ext_vector_type(4)));
typedef float f32x16 __attribute__((ext_vector_type(16)));
typedef unsigned int u32;
typedef unsigned int u32x4 __attribute__((ext_vector_type(4)));
typedef unsigned short u16x4 __attribute__((ext_vector_type(4)));
typedef unsigned long long u64;

#define LOG2E 1.4426950408889634f
#define QSCALE 0.18033688011112042f  // 0.125 * log2(e)
#define NEG_BIG -3.0e38f

#define PKS(dst, a, b) asm("v_cvt_pk_bf16_f32 %0, %1, %2" : "=v"(dst) : "v"(a), "v"(b))
#define SWP(x, y) asm("v_permlane32_swap_b32 %0, %1" : "+v"(x), "+v"(y))

__device__ __forceinline__ unsigned short f2b(float f) {
    unsigned int u = __float_as_uint(f);
    unsigned int r = (u + 0x7fffu + ((u >> 16) & 1u)) >> 16;
    return (unsigned short)r;
}

__device__ __forceinline__ void g2l16(const void* g, void* l) {
    __builtin_amdgcn_global_load_lds(
        (const __attribute__((address_space(1))) unsigned int*)(g),
        (__attribute__((address_space(3))) unsigned int*)(l), 16, 0, 0);
}

// ---------------- weight prep: Wqkv^T, Wout^T, bias table ----------------
// r22: bias table pre-shifted by -8 (fixed softmax reference; no running max).
__global__ __launch_bounds__(256) void k_prepw(const float* __restrict__ Wqkv,
                                               unsigned short* __restrict__ wqkvT,
                                               const float* __restrict__ Wout,
                                               unsigned short* __restrict__ woutT,
                                               const float* __restrict__ W1,
                                               const float* __restrict__ b1,
                                               const float* __restrict__ W2,
                                               float* __restrict__ btab) {
    int bid = blockIdx.x, tid = threadIdx.x;
    {
        int idx = bid * 256 + tid;           // 786432 elements
        int k = idx & 511, n = idx >> 9;
        wqkvT[idx] = f2b(Wqkv[(long)k * 1536 + n]);
    }
    if (bid < 1024) {
        int idx = bid * 256 + tid;           // 262144 elements
        int k = idx & 511, n = idx >> 9;
        woutT[idx] = f2b(Wout[(long)k * 512 + n]);
    }
    if (bid >= 3064) {
        int idx = (bid - 3064) * 256 + tid;  // 0..2047
        if (idx <= 2045) {
            float t = 0.0f;
            if (idx != 2045) {
                float r = (float)(idx - 1022) * (8.0f / 1022.0f);
                float sg = (r > 0.f) ? 1.0f : ((r < 0.f) ? -1.0f : 0.0f);
                t = sg * log2f(fabsf(r) + 1.0f) * 0.3154648767971406f;  // 1/log2(9)
            }
            float acc[8] = {0, 0, 0, 0, 0, 0, 0, 0};
            float accc[8] = {0, 0, 0, 0, 0, 0, 0, 0};
            for (int j = 0; j < 64; ++j) {
                float hj = t * W1[j] + b1[j];
                hj = (hj > 0.f) ? hj : 0.2f * hj;
                float hc = b1[j];
                hc = (hc > 0.f) ? hc : 0.2f * hc;
                #pragma unroll
                for (int h = 0; h < 8; ++h) {
                    acc[h] += hj * W2[j * 8 + h];
                    accc[h] += hc * W2[j * 8 + h];
                }
            }
            #pragma unroll
            for (int h = 0; h < 8; ++h) {
                btab[h * 4096 + idx] = acc[h] * LOG2E - 8.0f;
                btab[h * 4096 + 2048 + idx] = accc[h] * LOG2E - 8.0f;
            }
        }
    }
}

// ---------------- GEMM: C = A @ BT^T, bf16 MFMA ----------------
template <int MODE>
__global__ __launch_bounds__(256) void k_gemm(const float* __restrict__ Af,
                                              const unsigned short* __restrict__ A16,
                                              const unsigned short* __restrict__ BT,
                                              int M, int N,
                                              unsigned short* __restrict__ Qp,
                                              unsigned short* __restrict__ Kp,
                                              unsigned short* __restrict__ VTp,
                                              float* __restrict__ Cout) {
    __shared__ __align__(16) unsigned short As[2][128 * 32];
    __shared__ __align__(16) unsigned short Bs[2][128 * 32];
    constexpr int NX = (MODE == 0) ? 12 : 4;      // N/128
    constexpr int NWG = (MODE == 0) ? 1536 : 512; // total workgroups (div by 8)
    int lid = blockIdx.y * NX + blockIdx.x;       // linear dispatch index (x fastest)
    int tile = (lid & 7) * (NWG >> 3) + (lid >> 3);
    int m0 = (tile / NX) * 128, n0 = (tile % NX) * 128;
    int tid = threadIdx.x;
    int wave = tid >> 6, lane = tid & 63, lr = lane & 15, g = lane >> 4;
    int wr = wave >> 1, wc = wave & 1;
    f32x4 acc[4][4] = {};
    const float* Af0 = Af + (long)(m0 + (tid >> 2)) * 512 + (tid & 3) * 8;
    const float* Af1 = Af0 + 64 * 512;
    const char* Ab = (const char*)A16 + (long)(m0 + (tid >> 2)) * 1024 + (tid & 3) * 16;
    const char* Bb = (const char*)BT + (long)(n0 + (tid >> 2)) * 1024 + (tid & 3) * 16;

    // prologue: stage tile 0 into buffer 0
    if (MODE == 0) {
        f32x4 a0 = *(const f32x4*)(Af0);
        f32x4 a1 = *(const f32x4*)(Af0 + 4);
        f32x4 a2 = *(const f32x4*)(Af1);
        f32x4 a3 = *(const f32x4*)(Af1 + 4);
        u32 w0, w1, w2, w3;
        PKS(w0, a0.x, a0.y); PKS(w1, a0.z, a0.w);
        PKS(w2, a1.x, a1.y); PKS(w3, a1.z, a1.w);
        *(u32x4*)((char*)As[0] + tid * 16) = u32x4{w0, w1, w2, w3};
        PKS(w0, a2.x, a2.y); PKS(w1, a2.z, a2.w);
        PKS(w2, a3.x, a3.y); PKS(w3, a3.z, a3.w);
        *(u32x4*)((char*)As[0] + 4096 + tid * 16) = u32x4{w0, w1, w2, w3};
    } else {
        g2l16(Ab, (char*)As[0] + wave * 1024);
        g2l16(Ab + 65536, (char*)As[0] + 4096 + wave * 1024);
    }
    g2l16(Bb, (char*)Bs[0] + wave * 1024);
    g2l16(Bb + 65536, (char*)Bs[0] + 4096 + wave * 1024);
    __syncthreads();

    for (int kt = 0; kt < 16; ++kt) {
        int cur = kt & 1;
        int nxt = cur ^ 1;
        f32x4 na0, na1, na2, na3;
        if (kt < 15) {
            if (MODE == 0) {
                na0 = *(const f32x4*)(Af0 + (kt + 1) * 32);
                na1 = *(const f32x4*)(Af0 + (kt + 1) * 32 + 4);
                na2 = *(const f32x4*)(Af1 + (kt + 1) * 32);
                na3 = *(const f32x4*)(Af1 + (kt + 1) * 32 + 4);
            } else {
                g2l16(Ab + (kt + 1) * 64, (char*)As[nxt] + wave * 1024);
                g2l16(Ab + 65536 + (kt + 1) * 64, (char*)As[nxt] + 4096 + wave * 1024);
            }
            g2l16(Bb + (kt + 1) * 64, (char*)Bs[nxt] + wave * 1024);
            g2l16(Bb + 65536 + (kt + 1) * 64, (char*)Bs[nxt] + 4096 + wave * 1024);
        }
        s16x8 av[4], bv[4];
        #pragma unroll
        for (int f = 0; f < 4; ++f) {
            av[f] = *(const s16x8*)((char*)As[cur] + (wr * 64 + f * 16 + lr) * 64 + g * 16);
            bv[f] = *(const s16x8*)((char*)Bs[cur] + (wc * 64 + f * 16 + lr) * 64 + g * 16);
        }
        __builtin_amdgcn_s_setprio(1);
        #pragma unroll
        for (int fi = 0; fi < 4; ++fi)
            #pragma unroll
            for (int fj = 0; fj < 4; ++fj)
                acc[fi][fj] = __builtin_amdgcn_mfma_f32_16x16x32_bf16(bv[fj], av[fi], acc[fi][fj], 0, 0, 0);
        __builtin_amdgcn_s_setprio(0);
        if (MODE == 0 && kt < 15) {
            u32 w0, w1, w2, w3;
            PKS(w0, na0.x, na0.y); PKS(w1, na0.z, na0.w);
            PKS(w2, na1.x, na1.y); PKS(w3, na1.z, na1.w);
            *(u32x4*)((char*)As[nxt] + tid * 16) = u32x4{w0, w1, w2, w3};
            PKS(w0, na2.x, na2.y); PKS(w1, na2.z, na2.w);
            PKS(w2, na3.x, na3.y); PKS(w3, na3.z, na3.w);
            *(u32x4*)((char*)As[nxt] + 4096 + tid * 16) = u32x4{w0, w1, w2, w3};
        }
        __syncthreads();
    }
    // epilogue (swapped layout): lane holds C[gm = m0+wr*64+fi*16+lr][n = n0+wc*64+fj*16+g*4+e]
    #pragma unroll
    for (int fi = 0; fi < 4; ++fi) {
        int gm = m0 + wr * 64 + fi * 16 + lr;
        if (MODE == 0) {
            int bq = gm >> 10, lp = gm & 1023;
            int kvt = lp >> 6, kvl = lp & 63;
            #pragma unroll
            for (int fj = 0; fj < 4; ++fj) {
                int col0 = n0 + wc * 64 + fj * 16 + g * 4;  // 4-aligned; sec/h constant over e
                int sec = col0 >> 9, c0 = col0 & 511, h = c0 >> 6, dd0 = c0 & 63;
                int bh = bq * 8 + h;
                float v0 = acc[fi][fj][0], v1 = acc[fi][fj][1];
                float v2 = acc[fi][fj][2], v3 = acc[fi][fj][3];
                if (sec == 0) {
                    u32 w0, w1;
                    float q0 = v0 * QSCALE, q1 = v1 * QSCALE, q2 = v2 * QSCALE, q3 = v3 * QSCALE;
                    PKS(w0, q0, q1); PKS(w1, q2, q3);
                    *(uint2*)(Qp + (long)(bh * 1024 + lp) * 64 + dd0) = make_uint2(w0, w1);
                } else if (sec == 1) {
                    u32 w0, w1;
                    PKS(w0, v0, v1); PKS(w1, v2, v3);
                    long off = (long)bh * 65536 + kvt * 4096 + (kvl >> 5) * 2048 +
                               (dd0 >> 4) * 512 + ((((dd0 >> 3) & 1) << 5) + (kvl & 31)) * 8 + (dd0 & 7);
                    *(uint2*)(Kp + off) = make_uint2(w0, w1);
                } else {
                    // VT fragment-linear: consecutive dd -> stride 8 shorts
                    long off = (long)bh * 65536 + kvt * 4096 + (dd0 >> 5) * 2048 +
                               (kvl >> 4) * 512 + ((((kvl >> 3) & 1) << 5) + (dd0 & 31)) * 8 + (kvl & 7);
                    VTp[off] = f2b(v0);
                    VTp[off + 8] = f2b(v1);
                    VTp[off + 16] = f2b(v2);
                    VTp[off + 24] = f2b(v3);
                }
            }
        } else {
            #pragma unroll
            for (int fj = 0; fj < 4; ++fj) {
                int col0 = n0 + wc * 64 + fj * 16 + g * 4;
                *(f32x4*)(Cout + (long)gm * N + col0) = acc[fi][fj];
            }
        }
    }
}

// ---------------- flash attention ----------------
// r25 frame + r26: real counted-vmcnt discipline.
//  (a) bias loads issued BEFORE STAGE(t+2): the compiler's bias-value waits now
//      retire only older ops (vmcnt<=2), leaving the 2 stage loads in flight —
//      previously the bias waits (stages issued first) drained the stage every iter.
//  (b) odd-iter sync = s_waitcnt vmcnt(2) + raw s_barrier + sched_barrier(0)
//      (no vmcnt(0) drain). Slot-parity safety proof as r24; each wave's own
//      bias-wait retired stage(t+1) before its barrier. Final iter keeps full
//      __syncthreads before the epilogue's LDS reuse.
#define ATT_STAGE(MTT) do { \
    char* Kn_ = smem + ((MTT) & 3) * 16384; \
    g2l16(Kg + (MTT) * 8192 + tid * 16, Kn_ + wave * 1024); \
    g2l16(Vg + (MTT) * 8192 + tid * 16, Kn_ + 8192 + wave * 1024); \
  } while (0)

#define ATT_PV(VPTR) do { \
    __builtin_amdgcn_s_setprio(1); \
    o0 = __builtin_amdgcn_mfma_f32_32x32x16_bf16(*(const s16x8*)((VPTR) + lx), Pc0, o0, 0, 0, 0); \
    o0 = __builtin_amdgcn_mfma_f32_32x32x16_bf16(*(const s16x8*)((VPTR) + 1024 + lx), Pc1, o0, 0, 0, 0); \
    o0 = __builtin_amdgcn_mfma_f32_32x32x16_bf16(*(const s16x8*)((VPTR) + 2048 + lx), Pc2, o0, 0, 0, 0); \
    o0 = __builtin_amdgcn_mfma_f32_32x32x16_bf16(*(const s16x8*)((VPTR) + 3072 + lx), Pc3, o0, 0, 0, 0); \
    o1 = __builtin_amdgcn_mfma_f32_32x32x16_bf16(*(const s16x8*)((VPTR) + 4096 + lx), Pc0, o1, 0, 0, 0); \
    o1 = __builtin_amdgcn_mfma_f32_32x32x16_bf16(*(const s16x8*)((VPTR) + 5120 + lx), Pc1, o1, 0, 0, 0); \
    o1 = __builtin_amdgcn_mfma_f32_32x32x16_bf16(*(const s16x8*)((VPTR) + 6144 + lx), Pc2, o1, 0, 0, 0); \
    o1 = __builtin_amdgcn_mfma_f32_32x32x16_bf16(*(const s16x8*)((VPTR) + 7168 + lx), Pc3, o1, 0, 0, 0); \
    Sacc = __builtin_amdgcn_mfma_f32_32x32x16_bf16(ones8, Pc0, Sacc, 0, 0, 0); \
    Sacc = __builtin_amdgcn_mfma_f32_32x32x16_bf16(ones8, Pc1, Sacc, 0, 0, 0); \
    Sacc = __builtin_amdgcn_mfma_f32_32x32x16_bf16(ones8, Pc2, Sacc, 0, 0, 0); \
    Sacc = __builtin_amdgcn_mfma_f32_32x32x16_bf16(ones8, Pc3, Sacc, 0, 0, 0); \
    __builtin_amdgcn_s_setprio(0); \
  } while (0)

// BAR: 0 = none, 1 = counted-vmcnt raw barrier, 2 = full __syncthreads
#define ATT_ITER(MT, BAR) do { \
    int ib = (MT) * 64 - l + 1022; \
    float b0[16], b1v[16]; \
    { \
        const float* bq = bp + ib + 4 * hi; \
        _Pragma("unroll") \
        for (int k = 0; k < 4; ++k) { \
            f32x4 va = *(const f32x4*)(bq + 8 * k); \
            f32x4 vb = *(const f32x4*)(bq + 32 + 8 * k); \
            b0[4 * k + 0] = va.x; b0[4 * k + 1] = va.y; \
            b0[4 * k + 2] = va.z; b0[4 * k + 3] = va.w; \
            b1v[4 * k + 0] = vb.x; b1v[4 * k + 1] = vb.y; \
            b1v[4 * k + 2] = vb.z; b1v[4 * k + 3] = vb.w; \
        } \
    } \
    if ((MT) + 2 < 16) ATT_STAGE((MT) + 2); \
    char* Kl = smem + ((MT) & 3) * 16384; \
    f32x16 s0 = {}, s1 = {}; \
    __builtin_amdgcn_s_setprio(1); \
    s0 = __builtin_amdgcn_mfma_f32_32x32x16_bf16(*(const s16x8*)(Kl + lx), qf0, s0, 0, 0, 0); \
    s0 = __builtin_amdgcn_mfma_f32_32x32x16_bf16(*(const s16x8*)(Kl + 1024 + lx), qf1, s0, 0, 0, 0); \
    s0 = __builtin_amdgcn_mfma_f32_32x32x16_bf16(*(const s16x8*)(Kl + 2048 + lx), qf2, s0, 0, 0, 0); \
    s0 = __builtin_amdgcn_mfma_f32_32x32x16_bf16(*(const s16x8*)(Kl + 3072 + lx), qf3, s0, 0, 0, 0); \
    s1 = __builtin_amdgcn_mfma_f32_32x32x16_bf16(*(const s16x8*)(Kl + 4096 + lx), qf0, s1, 0, 0, 0); \
    s1 = __builtin_amdgcn_mfma_f32_32x32x16_bf16(*(const s16x8*)(Kl + 5120 + lx), qf1, s1, 0, 0, 0); \
    s1 = __builtin_amdgcn_mfma_f32_32x32x16_bf16(*(const s16x8*)(Kl + 6144 + lx), qf2, s1, 0, 0, 0); \
    s1 = __builtin_amdgcn_mfma_f32_32x32x16_bf16(*(const s16x8*)(Kl + 7168 + lx), qf3, s1, 0, 0, 0); \
    __builtin_amdgcn_s_setprio(0); \
    u64 mb = *(const u64*)(smem + 65536 + (MT) * 8); \
    u32 wm0 = (u32)(mb >> (4 * hi)); \
    u32 wm1 = (u32)(mb >> (32 + 4 * hi)); \
    if ((MT) == 0 && hi == 0) b0[0] = c2; \
    _Pragma("unroll") \
    for (int r = 0; r < 16; ++r) { \
        int pos = (r & 3) + 8 * (r >> 2); \
        s0[r] = ((wm0 >> pos) & 1) ? s0[r] + b0[r] : NEG_BIG; \
        s1[r] = ((wm1 >> pos) & 1) ? s1[r] + b1v[r] : NEG_BIG; \
    } \
    _Pragma("unroll") \
    for (int r = 0; r < 16; ++r) s0[r] = __builtin_amdgcn_exp2f(s0[r]); \
    _Pragma("unroll") \
    for (int r = 0; r < 16; ++r) s1[r] = __builtin_amdgcn_exp2f(s1[r]); \
    { \
        u32 x, y, x2, y2; \
        union { u32 w[4]; s16x8 v; } pt; \
        PKS(x, s0[0], s0[1]);  PKS(y, s0[4], s0[5]);  SWP(x, y); \
        PKS(x2, s0[2], s0[3]); PKS(y2, s0[6], s0[7]); SWP(x2, y2); \
        pt.w[0] = x; pt.w[1] = x2; pt.w[2] = y; pt.w[3] = y2; Pc0 = pt.v; \
        PKS(x, s0[8], s0[9]);   PKS(y, s0[12], s0[13]);  SWP(x, y); \
        PKS(x2, s0[10], s0[11]); PKS(y2, s0[14], s0[15]); SWP(x2, y2); \
        pt.w[0] = x; pt.w[1] = x2; pt.w[2] = y; pt.w[3] = y2; Pc1 = pt.v; \
        PKS(x, s1[0], s1[1]);  PKS(y, s1[4], s1[5]);  SWP(x, y); \
        PKS(x2, s1[2], s1[3]); PKS(y2, s1[6], s1[7]); SWP(x2, y2); \
        pt.w[0] = x; pt.w[1] = x2; pt.w[2] = y; pt.w[3] = y2; Pc2 = pt.v; \
        PKS(x, s1[8], s1[9]);   PKS(y, s1[12], s1[13]);  SWP(x, y); \
        PKS(x2, s1[10], s1[11]); PKS(y2, s1[14], s1[15]); SWP(x2, y2); \
        pt.w[0] = x; pt.w[1] = x2; pt.w[2] = y; pt.w[3] = y2; Pc3 = pt.v; \
    } \
    { \
        char* Vp_ = smem + ((MT) & 3) * 16384 + 8192; \
        ATT_PV(Vp_); \
    } \
    if ((BAR) == 2) { \
        __syncthreads(); \
    } else if ((BAR) == 1) { \
        asm volatile("s_waitcnt vmcnt(2)" ::: "memory"); \
        __builtin_amdgcn_s_barrier(); \
        __builtin_amdgcn_sched_barrier(0); \
    } \
  } while (0)

__global__ __launch_bounds__(512, 2) void k_attn(const unsigned short* __restrict__ Q,
                                                 const unsigned short* __restrict__ Kb,
                                                 const unsigned short* __restrict__ VT,
                                                 const int* __restrict__ mask,
                                                 const float* __restrict__ btab,
                                                 unsigned short* __restrict__ AO) {
    __shared__ __align__(16) char smem[65664];  // 4x16K ring + mask @65536 (cap=2/CU via LDS)
    int lid = blockIdx.x;
    int wg = (lid & 7) * 64 + (lid >> 3);   // bijective XCD swizzle (512 = 8*64)
    int qt = wg & 3, bh = wg >> 2;
    int b = bh >> 3, h = bh & 7;
    int tid = threadIdx.x;
    int wave = tid >> 6, lane = tid & 63;
    int q = lane & 31, hi = lane >> 5;
    int l = qt * 256 + wave * 32 + q;
    const float* bt = btab + h * 4096;
    float c2 = bt[2045];
    const float* bp = bt + ((l == 0) ? 2048 : 0);

    const char* Kg = (const char*)Kb + (long)bh * 131072;
    const char* Vg = (const char*)VT + (long)bh * 131072;

    // mask bitmasks -> LDS (one u64 per 64-kv tile)
    if (tid < 16) {
        const int* mrow = mask + b * 1023;
        u64 bits = 0;
        for (int j = 0; j < 64; ++j) {
            int kv = tid * 64 + j;
            int bit = (kv == 0) ? 1 : (mrow[kv - 1] != 0);
            bits |= (u64)bit << j;
        }
        *(u64*)(smem + 65536 + tid * 8) = bits;
    }

    // Q fragments (B-operand): col=q, k = d = ko*16 + hi*8 + e
    const char* Qrow = (const char*)Q + ((long)bh * 1024 + l) * 128;
    s16x8 qf0 = *(const s16x8*)(Qrow + 0 * 32 + hi * 16);
    s16x8 qf1 = *(const s16x8*)(Qrow + 1 * 32 + hi * 16);
    s16x8 qf2 = *(const s16x8*)(Qrow + 2 * 32 + hi * 16);
    s16x8 qf3 = *(const s16x8*)(Qrow + 3 * 32 + hi * 16);

    f32x16 o0 = {}, o1 = {}, Sacc = {};
    int lx = lane * 16;
    s16x8 Pc0 = {}, Pc1 = {}, Pc2 = {}, Pc3 = {};  // carried P (plain VGPR vectors)
    s16x8 ones8;
    {
        union { u32 w[4]; s16x8 v; } ou;
        ou.w[0] = ou.w[1] = ou.w[2] = ou.w[3] = 0x3F803F80u;  // bf16 1.0 x8
        ones8 = ou.v;
    }

    // prologue: stage tiles 0,1 (ring slots 0,1)
    ATT_STAGE(0);
    ATT_STAGE(1);
    __syncthreads();

    ATT_ITER(0, 0);  ATT_ITER(1, 1);  ATT_ITER(2, 0);  ATT_ITER(3, 1);
    ATT_ITER(4, 0);  ATT_ITER(5, 1);  ATT_ITER(6, 0);  ATT_ITER(7, 1);
    ATT_ITER(8, 0);  ATT_ITER(9, 1);  ATT_ITER(10, 0); ATT_ITER(11, 1);
    ATT_ITER(12, 0); ATT_ITER(13, 1); ATT_ITER(14, 0); ATT_ITER(15, 2);

    // epilogue: normalize, transpose via LDS, coalesced store
    // (full __syncthreads after iter 15 ordered all ring reads vs the reuse below)
    float Ss = Sacc[0];
    float inv = 1.0f / Ss;
    char* Ob = smem;
    int qloc = wave * 32 + q;
    #pragma unroll
    for (int j = 0; j < 4; ++j) {
        u32 wa, wb;
        float va0 = o0[j * 4 + 0] * inv, va1 = o0[j * 4 + 1] * inv;
        float va2 = o0[j * 4 + 2] * inv, va3 = o0[j * 4 + 3] * inv;
        PKS(wa, va0, va1); PKS(wb, va2, va3);
        int d0 = 8 * j + 4 * hi;
        *(uint2*)(Ob + qloc * 128 + ((d0 * 2) ^ ((qloc & 7) << 4))) = make_uint2(wa, wb);
    }
    #pragma unroll
    for (int j = 0; j < 4; ++j) {
        u32 wa, wb;
        float va0 = o1[j * 4 + 0] * inv, va1 = o1[j * 4 + 1] * inv;
        float va2 = o1[j * 4 + 2] * inv, va3 = o1[j * 4 + 3] * inv;
        PKS(wa, va0, va1); PKS(wb, va2, va3);
        int d0 = 32 + 8 * j + 4 * hi;
        *(uint2*)(Ob + qloc * 128 + ((d0 * 2) ^ ((qloc & 7) << 4))) = make_uint2(wa, wb);
    }
    __syncthreads();
    long gb = (long)(b * 1024 + qt * 256) * 512 + h * 64;
    #pragma unroll
    for (int p = 0; p < 4; ++p) {
        int qr = p * 64 + (tid >> 3);
        int ss = tid & 7;
        u32x4 vv = *(const u32x4*)(Ob + qr * 128 + ((ss * 16) ^ ((qr & 7) << 4)));
        *(u32x4*)((char*)AO + (gb + (long)qr * 512 + ss * 8) * 2) = vv;
    }
}

// ---------------- launch ----------------

extern "C" void kernel_launch(void* const* d_in, const int* in_sizes, int n_in,
                              void* d_out, int out_size, void* d_ws, size_t ws_size,
                              hipStream_t stream) {
    const float* x    = (const float*)d_in[0];
    const int*   mask = (const int*)d_in[1];
    const float* Wqkv = (const float*)d_in[2];
    const float* W1   = (const float*)d_in[3];
    const float* b1   = (const float*)d_in[4];
    const float* W2   = (const float*)d_in[5];
    const float* Wout = (const float*)d_in[6];
    float* out = (float*)d_out;
    char* ws = (char*)d_ws;

    unsigned short* wqkvT = (unsigned short*)(ws + 16777216);  // 1.5 MB [1536][512]
    unsigned short* woutT = (unsigned short*)(ws + 18350080);  // 0.5 MB [512][512]
    unsigned short* Qb    = (unsigned short*)(ws + 18874368);  // 16 MB [bh][l][d]
    unsigned short* Kb    = (unsigned short*)(ws + 35651584);  // 16 MB fragment-linear
    unsigned short* VTb   = (unsigned short*)(ws + 52428800);  // 16 MB fragment-linear
    unsigned short* AOb   = (unsigned short*)(ws + 69206016);  // 16 MB [16384][512]
    float* btab           = (float*)(ws + 85983232);           // 128 KB (tail region)
    if (ws_size < 86114304) return;

    k_prepw<<<3072, 256, 0, stream>>>(Wqkv, wqkvT, Wout, woutT, W1, b1, W2, btab);
    k_gemm<0><<<dim3(12, 128), 256, 0, stream>>>(x, nullptr, wqkvT, 16384, 1536, Qb, Kb, VTb, nullptr);
    k_attn<<<512, 512, 0, stream>>>(Qb, Kb, VTb, mask, btab, AOb);
    k_gemm<1><<<dim3(4, 128), 256, 0, stream>>>(nullptr, AOb, woutT, 16384, 512, nullptr, nullptr, nullptr, out);
}

// Round 27
// 135.353 us; speedup vs baseline: 1.0997x; 1.0372x over previous
//
#include <hip/hip_runtime.h>
#include <hip/hip_bf16.h>

typedef short s16x8 __attribute__((ext_vector_type(8)));
typedef float f32x4 __attribute__((ext_vector_type(4)));
typedef float f32x16 __attribute__((ext_vector_type(16)));
typedef unsigned int u32;
typedef unsigned int u32x4 __attribute__((ext_vector_type(4)));
typedef unsigned short u16x4 __attribute__((ext_vector_type(4)));
typedef unsigned long long u64;

#define LOG2E 1.4426950408889634f
#define QSCALE 0.18033688011112042f  // 0.125 * log2(e)
#define NEG_BIG -3.0e38f

#define PKS(dst, a, b) asm("v_cvt_pk_bf16_f32 %0, %1, %2" : "=v"(dst) : "v"(a), "v"(b))
#define SWP(x, y) asm("v_permlane32_swap_b32 %0, %1" : "+v"(x), "+v"(y))

__device__ __forceinline__ unsigned short f2b(float f) {
    unsigned int u = __float_as_uint(f);
    unsigned int r = (u + 0x7fffu + ((u >> 16) & 1u)) >> 16;
    return (unsigned short)r;
}

__device__ __forceinline__ void g2l16(const void* g, void* l) {
    __builtin_amdgcn_global_load_lds(
        (const __attribute__((address_space(1))) unsigned int*)(g),
        (__attribute__((address_space(3))) unsigned int*)(l), 16, 0, 0);
}

// ---------------- weight prep: Wqkv^T, Wout^T (LDS tile transpose), bias table ----------------
// r27: 64x64 f32 LDS tile transpose — coalesced row reads, coalesced bf16 column
// writes (was: stride-6144B scalar gathers, 64B fetched per 4B used).
// Grid: 192 Wqkv tiles (24n x 8k) + 64 Wout tiles (8n x 8k) + 8 bias blocks = 264.
__global__ __launch_bounds__(256) void k_prepw(const float* __restrict__ Wqkv,
                                               unsigned short* __restrict__ wqkvT,
                                               const float* __restrict__ Wout,
                                               unsigned short* __restrict__ woutT,
                                               const float* __restrict__ W1,
                                               const float* __restrict__ b1,
                                               const float* __restrict__ W2,
                                               float* __restrict__ btab) {
    __shared__ float tl[64][65];
    int bid = blockIdx.x, tid = threadIdx.x;
    if (bid < 256) {
        const float* W;
        unsigned short* WT;
        int NCOL, tile_k, tile_n;
        if (bid < 192) {
            W = Wqkv; WT = wqkvT; NCOL = 1536;
            tile_n = (bid % 24) * 64; tile_k = (bid / 24) * 64;
        } else {
            W = Wout; WT = woutT; NCOL = 512;
            int tb = bid - 192;
            tile_n = (tb % 8) * 64; tile_k = (tb / 8) * 64;
        }
        int rr = tid >> 4;          // 0..15
        int cc = (tid & 15) * 4;    // 0,4,...,60
        #pragma unroll
        for (int ri = 0; ri < 4; ++ri) {
            int r = ri * 16 + rr;
            f32x4 v = *(const f32x4*)(W + (long)(tile_k + r) * NCOL + tile_n + cc);
            tl[r][cc + 0] = v.x; tl[r][cc + 1] = v.y;
            tl[r][cc + 2] = v.z; tl[r][cc + 3] = v.w;
        }
        __syncthreads();
        #pragma unroll
        for (int ri = 0; ri < 4; ++ri) {
            int r2 = ri * 16 + rr;       // n within tile
            float v0 = tl[cc + 0][r2], v1 = tl[cc + 1][r2];
            float v2 = tl[cc + 2][r2], v3 = tl[cc + 3][r2];
            u32 w0, w1;
            PKS(w0, v0, v1); PKS(w1, v2, v3);
            *(uint2*)(WT + (long)(tile_n + r2) * 512 + tile_k + cc) = make_uint2(w0, w1);
        }
        return;
    }
    int idx = (bid - 256) * 256 + tid;  // 0..2047
    if (idx <= 2045) {
        float t = 0.0f;
        if (idx != 2045) {
            float r = (float)(idx - 1022) * (8.0f / 1022.0f);
            float sg = (r > 0.f) ? 1.0f : ((r < 0.f) ? -1.0f : 0.0f);
            t = sg * log2f(fabsf(r) + 1.0f) * 0.3154648767971406f;  // 1/log2(9)
        }
        float acc[8] = {0, 0, 0, 0, 0, 0, 0, 0};
        float accc[8] = {0, 0, 0, 0, 0, 0, 0, 0};
        for (int j = 0; j < 64; ++j) {
            float hj = t * W1[j] + b1[j];
            hj = (hj > 0.f) ? hj : 0.2f * hj;
            float hc = b1[j];
            hc = (hc > 0.f) ? hc : 0.2f * hc;
            #pragma unroll
            for (int h = 0; h < 8; ++h) {
                acc[h] += hj * W2[j * 8 + h];
                accc[h] += hc * W2[j * 8 + h];
            }
        }
        #pragma unroll
        for (int h = 0; h < 8; ++h) {
            btab[h * 4096 + idx] = acc[h] * LOG2E - 8.0f;
            btab[h * 4096 + 2048 + idx] = accc[h] * LOG2E - 8.0f;
        }
    }
}

// ---------------- GEMM: C = A @ BT^T, bf16 MFMA ----------------
template <int MODE>
__global__ __launch_bounds__(256) void k_gemm(const float* __restrict__ Af,
                                              const unsigned short* __restrict__ A16,
                                              const unsigned short* __restrict__ BT,
                                              int M, int N,
                                              unsigned short* __restrict__ Qp,
                                              unsigned short* __restrict__ Kp,
                                              unsigned short* __restrict__ VTp,
                                              float* __restrict__ Cout) {
    __shared__ __align__(16) unsigned short As[2][128 * 32];
    __shared__ __align__(16) unsigned short Bs[2][128 * 32];
    constexpr int NX = (MODE == 0) ? 12 : 4;      // N/128
    constexpr int NWG = (MODE == 0) ? 1536 : 512; // total workgroups (div by 8)
    int lid = blockIdx.y * NX + blockIdx.x;       // linear dispatch index (x fastest)
    int tile = (lid & 7) * (NWG >> 3) + (lid >> 3);
    int m0 = (tile / NX) * 128, n0 = (tile % NX) * 128;
    int tid = threadIdx.x;
    int wave = tid >> 6, lane = tid & 63, lr = lane & 15, g = lane >> 4;
    int wr = wave >> 1, wc = wave & 1;
    f32x4 acc[4][4] = {};
    const float* Af0 = Af + (long)(m0 + (tid >> 2)) * 512 + (tid & 3) * 8;
    const float* Af1 = Af0 + 64 * 512;
    const char* Ab = (const char*)A16 + (long)(m0 + (tid >> 2)) * 1024 + (tid & 3) * 16;
    const char* Bb = (const char*)BT + (long)(n0 + (tid >> 2)) * 1024 + (tid & 3) * 16;

    // prologue: stage tile 0 into buffer 0
    if (MODE == 0) {
        f32x4 a0 = *(const f32x4*)(Af0);
        f32x4 a1 = *(const f32x4*)(Af0 + 4);
        f32x4 a2 = *(const f32x4*)(Af1);
        f32x4 a3 = *(const f32x4*)(Af1 + 4);
        u32 w0, w1, w2, w3;
        PKS(w0, a0.x, a0.y); PKS(w1, a0.z, a0.w);
        PKS(w2, a1.x, a1.y); PKS(w3, a1.z, a1.w);
        *(u32x4*)((char*)As[0] + tid * 16) = u32x4{w0, w1, w2, w3};
        PKS(w0, a2.x, a2.y); PKS(w1, a2.z, a2.w);
        PKS(w2, a3.x, a3.y); PKS(w3, a3.z, a3.w);
        *(u32x4*)((char*)As[0] + 4096 + tid * 16) = u32x4{w0, w1, w2, w3};
    } else {
        g2l16(Ab, (char*)As[0] + wave * 1024);
        g2l16(Ab + 65536, (char*)As[0] + 4096 + wave * 1024);
    }
    g2l16(Bb, (char*)Bs[0] + wave * 1024);
    g2l16(Bb + 65536, (char*)Bs[0] + 4096 + wave * 1024);
    __syncthreads();

    for (int kt = 0; kt < 16; ++kt) {
        int cur = kt & 1;
        int nxt = cur ^ 1;
        f32x4 na0, na1, na2, na3;
        if (kt < 15) {
            if (MODE == 0) {
                na0 = *(const f32x4*)(Af0 + (kt + 1) * 32);
                na1 = *(const f32x4*)(Af0 + (kt + 1) * 32 + 4);
                na2 = *(const f32x4*)(Af1 + (kt + 1) * 32);
                na3 = *(const f32x4*)(Af1 + (kt + 1) * 32 + 4);
            } else {
                g2l16(Ab + (kt + 1) * 64, (char*)As[nxt] + wave * 1024);
                g2l16(Ab + 65536 + (kt + 1) * 64, (char*)As[nxt] + 4096 + wave * 1024);
            }
            g2l16(Bb + (kt + 1) * 64, (char*)Bs[nxt] + wave * 1024);
            g2l16(Bb + 65536 + (kt + 1) * 64, (char*)Bs[nxt] + 4096 + wave * 1024);
        }
        s16x8 av[4], bv[4];
        #pragma unroll
        for (int f = 0; f < 4; ++f) {
            av[f] = *(const s16x8*)((char*)As[cur] + (wr * 64 + f * 16 + lr) * 64 + g * 16);
            bv[f] = *(const s16x8*)((char*)Bs[cur] + (wc * 64 + f * 16 + lr) * 64 + g * 16);
        }
        __builtin_amdgcn_s_setprio(1);
        #pragma unroll
        for (int fi = 0; fi < 4; ++fi)
            #pragma unroll
            for (int fj = 0; fj < 4; ++fj)
                acc[fi][fj] = __builtin_amdgcn_mfma_f32_16x16x32_bf16(bv[fj], av[fi], acc[fi][fj], 0, 0, 0);
        __builtin_amdgcn_s_setprio(0);
        if (MODE == 0 && kt < 15) {
            u32 w0, w1, w2, w3;
            PKS(w0, na0.x, na0.y); PKS(w1, na0.z, na0.w);
            PKS(w2, na1.x, na1.y); PKS(w3, na1.z, na1.w);
            *(u32x4*)((char*)As[nxt] + tid * 16) = u32x4{w0, w1, w2, w3};
            PKS(w0, na2.x, na2.y); PKS(w1, na2.z, na2.w);
            PKS(w2, na3.x, na3.y); PKS(w3, na3.z, na3.w);
            *(u32x4*)((char*)As[nxt] + 4096 + tid * 16) = u32x4{w0, w1, w2, w3};
        }
        __syncthreads();
    }
    // epilogue (swapped layout): lane holds C[gm = m0+wr*64+fi*16+lr][n = n0+wc*64+fj*16+g*4+e]
    #pragma unroll
    for (int fi = 0; fi < 4; ++fi) {
        int gm = m0 + wr * 64 + fi * 16 + lr;
        if (MODE == 0) {
            int bq = gm >> 10, lp = gm & 1023;
            int kvt = lp >> 6, kvl = lp & 63;
            #pragma unroll
            for (int fj = 0; fj < 4; ++fj) {
                int col0 = n0 + wc * 64 + fj * 16 + g * 4;  // 4-aligned; sec/h constant over e
                int sec = col0 >> 9, c0 = col0 & 511, h = c0 >> 6, dd0 = c0 & 63;
                int bh = bq * 8 + h;
                float v0 = acc[fi][fj][0], v1 = acc[fi][fj][1];
                float v2 = acc[fi][fj][2], v3 = acc[fi][fj][3];
                if (sec == 0) {
                    u32 w0, w1;
                    float q0 = v0 * QSCALE, q1 = v1 * QSCALE, q2 = v2 * QSCALE, q3 = v3 * QSCALE;
                    PKS(w0, q0, q1); PKS(w1, q2, q3);
                    *(uint2*)(Qp + (long)(bh * 1024 + lp) * 64 + dd0) = make_uint2(w0, w1);
                } else if (sec == 1) {
                    u32 w0, w1;
                    PKS(w0, v0, v1); PKS(w1, v2, v3);
                    long off = (long)bh * 65536 + kvt * 4096 + (kvl >> 5) * 2048 +
                               (dd0 >> 4) * 512 + ((((dd0 >> 3) & 1) << 5) + (kvl & 31)) * 8 + (dd0 & 7);
                    *(uint2*)(Kp + off) = make_uint2(w0, w1);
                } else {
                    // VT fragment-linear: consecutive dd -> stride 8 shorts
                    long off = (long)bh * 65536 + kvt * 4096 + (dd0 >> 5) * 2048 +
                               (kvl >> 4) * 512 + ((((kvl >> 3) & 1) << 5) + (dd0 & 31)) * 8 + (kvl & 7);
                    VTp[off] = f2b(v0);
                    VTp[off + 8] = f2b(v1);
                    VTp[off + 16] = f2b(v2);
                    VTp[off + 24] = f2b(v3);
                }
            }
        } else {
            #pragma unroll
            for (int fj = 0; fj < 4; ++fj) {
                int col0 = n0 + wc * 64 + fj * 16 + g * 4;
                *(f32x4*)(Cout + (long)gm * N + col0) = acc[fi][fj];
            }
        }
    }
}

// ---------------- flash attention (r26 exact) ----------------
#define ATT_STAGE(MTT) do { \
    char* Kn_ = smem + ((MTT) & 3) * 16384; \
    g2l16(Kg + (MTT) * 8192 + tid * 16, Kn_ + wave * 1024); \
    g2l16(Vg + (MTT) * 8192 + tid * 16, Kn_ + 8192 + wave * 1024); \
  } while (0)

#define ATT_PV(VPTR) do { \
    __builtin_amdgcn_s_setprio(1); \
    o0 = __builtin_amdgcn_mfma_f32_32x32x16_bf16(*(const s16x8*)((VPTR) + lx), Pc0, o0, 0, 0, 0); \
    o0 = __builtin_amdgcn_mfma_f32_32x32x16_bf16(*(const s16x8*)((VPTR) + 1024 + lx), Pc1, o0, 0, 0, 0); \
    o0 = __builtin_amdgcn_mfma_f32_32x32x16_bf16(*(const s16x8*)((VPTR) + 2048 + lx), Pc2, o0, 0, 0, 0); \
    o0 = __builtin_amdgcn_mfma_f32_32x32x16_bf16(*(const s16x8*)((VPTR) + 3072 + lx), Pc3, o0, 0, 0, 0); \
    o1 = __builtin_amdgcn_mfma_f32_32x32x16_bf16(*(const s16x8*)((VPTR) + 4096 + lx), Pc0, o1, 0, 0, 0); \
    o1 = __builtin_amdgcn_mfma_f32_32x32x16_bf16(*(const s16x8*)((VPTR) + 5120 + lx), Pc1, o1, 0, 0, 0); \
    o1 = __builtin_amdgcn_mfma_f32_32x32x16_bf16(*(const s16x8*)((VPTR) + 6144 + lx), Pc2, o1, 0, 0, 0); \
    o1 = __builtin_amdgcn_mfma_f32_32x32x16_bf16(*(const s16x8*)((VPTR) + 7168 + lx), Pc3, o1, 0, 0, 0); \
    Sacc = __builtin_amdgcn_mfma_f32_32x32x16_bf16(ones8, Pc0, Sacc, 0, 0, 0); \
    Sacc = __builtin_amdgcn_mfma_f32_32x32x16_bf16(ones8, Pc1, Sacc, 0, 0, 0); \
    Sacc = __builtin_amdgcn_mfma_f32_32x32x16_bf16(ones8, Pc2, Sacc, 0, 0, 0); \
    Sacc = __builtin_amdgcn_mfma_f32_32x32x16_bf16(ones8, Pc3, Sacc, 0, 0, 0); \
    __builtin_amdgcn_s_setprio(0); \
  } while (0)

// BAR: 0 = none, 1 = counted-vmcnt raw barrier, 2 = full __syncthreads
#define ATT_ITER(MT, BAR) do { \
    int ib = (MT) * 64 - l + 1022; \
    float b0[16], b1v[16]; \
    { \
        const float* bq = bp + ib + 4 * hi; \
        _Pragma("unroll") \
        for (int k = 0; k < 4; ++k) { \
            f32x4 va = *(const f32x4*)(bq + 8 * k); \
            f32x4 vb = *(const f32x4*)(bq + 32 + 8 * k); \
            b0[4 * k + 0] = va.x; b0[4 * k + 1] = va.y; \
            b0[4 * k + 2] = va.z; b0[4 * k + 3] = va.w; \
            b1v[4 * k + 0] = vb.x; b1v[4 * k + 1] = vb.y; \
            b1v[4 * k + 2] = vb.z; b1v[4 * k + 3] = vb.w; \
        } \
    } \
    if ((MT) + 2 < 16) ATT_STAGE((MT) + 2); \
    char* Kl = smem + ((MT) & 3) * 16384; \
    f32x16 s0 = {}, s1 = {}; \
    __builtin_amdgcn_s_setprio(1); \
    s0 = __builtin_amdgcn_mfma_f32_32x32x16_bf16(*(const s16x8*)(Kl + lx), qf0, s0, 0, 0, 0); \
    s0 = __builtin_amdgcn_mfma_f32_32x32x16_bf16(*(const s16x8*)(Kl + 1024 + lx), qf1, s0, 0, 0, 0); \
    s0 = __builtin_amdgcn_mfma_f32_32x32x16_bf16(*(const s16x8*)(Kl + 2048 + lx), qf2, s0, 0, 0, 0); \
    s0 = __builtin_amdgcn_mfma_f32_32x32x16_bf16(*(const s16x8*)(Kl + 3072 + lx), qf3, s0, 0, 0, 0); \
    s1 = __builtin_amdgcn_mfma_f32_32x32x16_bf16(*(const s16x8*)(Kl + 4096 + lx), qf0, s1, 0, 0, 0); \
    s1 = __builtin_amdgcn_mfma_f32_32x32x16_bf16(*(const s16x8*)(Kl + 5120 + lx), qf1, s1, 0, 0, 0); \
    s1 = __builtin_amdgcn_mfma_f32_32x32x16_bf16(*(const s16x8*)(Kl + 6144 + lx), qf2, s1, 0, 0, 0); \
    s1 = __builtin_amdgcn_mfma_f32_32x32x16_bf16(*(const s16x8*)(Kl + 7168 + lx), qf3, s1, 0, 0, 0); \
    __builtin_amdgcn_s_setprio(0); \
    u64 mb = *(const u64*)(smem + 65536 + (MT) * 8); \
    u32 wm0 = (u32)(mb >> (4 * hi)); \
    u32 wm1 = (u32)(mb >> (32 + 4 * hi)); \
    if ((MT) == 0 && hi == 0) b0[0] = c2; \
    _Pragma("unroll") \
    for (int r = 0; r < 16; ++r) { \
        int pos = (r & 3) + 8 * (r >> 2); \
        s0[r] = ((wm0 >> pos) & 1) ? s0[r] + b0[r] : NEG_BIG; \
        s1[r] = ((wm1 >> pos) & 1) ? s1[r] + b1v[r] : NEG_BIG; \
    } \
    _Pragma("unroll") \
    for (int r = 0; r < 16; ++r) s0[r] = __builtin_amdgcn_exp2f(s0[r]); \
    _Pragma("unroll") \
    for (int r = 0; r < 16; ++r) s1[r] = __builtin_amdgcn_exp2f(s1[r]); \
    { \
        u32 x, y, x2, y2; \
        union { u32 w[4]; s16x8 v; } pt; \
        PKS(x, s0[0], s0[1]);  PKS(y, s0[4], s0[5]);  SWP(x, y); \
        PKS(x2, s0[2], s0[3]); PKS(y2, s0[6], s0[7]); SWP(x2, y2); \
        pt.w[0] = x; pt.w[1] = x2; pt.w[2] = y; pt.w[3] = y2; Pc0 = pt.v; \
        PKS(x, s0[8], s0[9]);   PKS(y, s0[12], s0[13]);  SWP(x, y); \
        PKS(x2, s0[10], s0[11]); PKS(y2, s0[14], s0[15]); SWP(x2, y2); \
        pt.w[0] = x; pt.w[1] = x2; pt.w[2] = y; pt.w[3] = y2; Pc1 = pt.v; \
        PKS(x, s1[0], s1[1]);  PKS(y, s1[4], s1[5]);  SWP(x, y); \
        PKS(x2, s1[2], s1[3]); PKS(y2, s1[6], s1[7]); SWP(x2, y2); \
        pt.w[0] = x; pt.w[1] = x2; pt.w[2] = y; pt.w[3] = y2; Pc2 = pt.v; \
        PKS(x, s1[8], s1[9]);   PKS(y, s1[12], s1[13]);  SWP(x, y); \
        PKS(x2, s1[10], s1[11]); PKS(y2, s1[14], s1[15]); SWP(x2, y2); \
        pt.w[0] = x; pt.w[1] = x2; pt.w[2] = y; pt.w[3] = y2; Pc3 = pt.v; \
    } \
    { \
        char* Vp_ = smem + ((MT) & 3) * 16384 + 8192; \
        ATT_PV(Vp_); \
    } \
    if ((BAR) == 2) { \
        __syncthreads(); \
    } else if ((BAR) == 1) { \
        asm volatile("s_waitcnt vmcnt(2)" ::: "memory"); \
        __builtin_amdgcn_s_barrier(); \
        __builtin_amdgcn_sched_barrier(0); \
    } \
  } while (0)

__global__ __launch_bounds__(512, 2) void k_attn(const unsigned short* __restrict__ Q,
                                                 const unsigned short* __restrict__ Kb,
                                                 const unsigned short* __restrict__ VT,
                                                 const int* __restrict__ mask,
                                                 const float* __restrict__ btab,
                                                 unsigned short* __restrict__ AO) {
    __shared__ __align__(16) char smem[65664];  // 4x16K ring + mask @65536 (cap=2/CU via LDS)
    int lid = blockIdx.x;
    int wg = (lid & 7) * 64 + (lid >> 3);   // bijective XCD swizzle (512 = 8*64)
    int qt = wg & 3, bh = wg >> 2;
    int b = bh >> 3, h = bh & 7;
    int tid = threadIdx.x;
    int wave = tid >> 6, lane = tid & 63;
    int q = lane & 31, hi = lane >> 5;
    int l = qt * 256 + wave * 32 + q;
    const float* bt = btab + h * 4096;
    float c2 = bt[2045];
    const float* bp = bt + ((l == 0) ? 2048 : 0);

    const char* Kg = (const char*)Kb + (long)bh * 131072;
    const char* Vg = (const char*)VT + (long)bh * 131072;

    // mask bitmasks -> LDS (one u64 per 64-kv tile)
    if (tid < 16) {
        const int* mrow = mask + b * 1023;
        u64 bits = 0;
        for (int j = 0; j < 64; ++j) {
            int kv = tid * 64 + j;
            int bit = (kv == 0) ? 1 : (mrow[kv - 1] != 0);
            bits |= (u64)bit << j;
        }
        *(u64*)(smem + 65536 + tid * 8) = bits;
    }

    // Q fragments (B-operand): col=q, k = d = ko*16 + hi*8 + e
    const char* Qrow = (const char*)Q + ((long)bh * 1024 + l) * 128;
    s16x8 qf0 = *(const s16x8*)(Qrow + 0 * 32 + hi * 16);
    s16x8 qf1 = *(const s16x8*)(Qrow + 1 * 32 + hi * 16);
    s16x8 qf2 = *(const s16x8*)(Qrow + 2 * 32 + hi * 16);
    s16x8 qf3 = *(const s16x8*)(Qrow + 3 * 32 + hi * 16);

    f32x16 o0 = {}, o1 = {}, Sacc = {};
    int lx = lane * 16;
    s16x8 Pc0 = {}, Pc1 = {}, Pc2 = {}, Pc3 = {};  // carried P (plain VGPR vectors)
    s16x8 ones8;
    {
        union { u32 w[4]; s16x8 v; } ou;
        ou.w[0] = ou.w[1] = ou.w[2] = ou.w[3] = 0x3F803F80u;  // bf16 1.0 x8
        ones8 = ou.v;
    }

    // prologue: stage tiles 0,1 (ring slots 0,1)
    ATT_STAGE(0);
    ATT_STAGE(1);
    __syncthreads();

    ATT_ITER(0, 0);  ATT_ITER(1, 1);  ATT_ITER(2, 0);  ATT_ITER(3, 1);
    ATT_ITER(4, 0);  ATT_ITER(5, 1);  ATT_ITER(6, 0);  ATT_ITER(7, 1);
    ATT_ITER(8, 0);  ATT_ITER(9, 1);  ATT_ITER(10, 0); ATT_ITER(11, 1);
    ATT_ITER(12, 0); ATT_ITER(13, 1); ATT_ITER(14, 0); ATT_ITER(15, 2);

    // epilogue: normalize, transpose via LDS, coalesced store
    // (full __syncthreads after iter 15 ordered all ring reads vs the reuse below)
    float Ss = Sacc[0];
    float inv = 1.0f / Ss;
    char* Ob = smem;
    int qloc = wave * 32 + q;
    #pragma unroll
    for (int j = 0; j < 4; ++j) {
        u32 wa, wb;
        float va0 = o0[j * 4 + 0] * inv, va1 = o0[j * 4 + 1] * inv;
        float va2 = o0[j * 4 + 2] * inv, va3 = o0[j * 4 + 3] * inv;
        PKS(wa, va0, va1); PKS(wb, va2, va3);
        int d0 = 8 * j + 4 * hi;
        *(uint2*)(Ob + qloc * 128 + ((d0 * 2) ^ ((qloc & 7) << 4))) = make_uint2(wa, wb);
    }
    #pragma unroll
    for (int j = 0; j < 4; ++j) {
        u32 wa, wb;
        float va0 = o1[j * 4 + 0] * inv, va1 = o1[j * 4 + 1] * inv;
        float va2 = o1[j * 4 + 2] * inv, va3 = o1[j * 4 + 3] * inv;
        PKS(wa, va0, va1); PKS(wb, va2, va3);
        int d0 = 32 + 8 * j + 4 * hi;
        *(uint2*)(Ob + qloc * 128 + ((d0 * 2) ^ ((qloc & 7) << 4))) = make_uint2(wa, wb);
    }
    __syncthreads();
    long gb = (long)(b * 1024 + qt * 256) * 512 + h * 64;
    #pragma unroll
    for (int p = 0; p < 4; ++p) {
        int qr = p * 64 + (tid >> 3);
        int ss = tid & 7;
        u32x4 vv = *(const u32x4*)(Ob + qr * 128 + ((ss * 16) ^ ((qr & 7) << 4)));
        *(u32x4*)((char*)AO + (gb + (long)qr * 512 + ss * 8) * 2) = vv;
    }
}

// ---------------- launch ----------------

extern "C" void kernel_launch(void* const* d_in, const int* in_sizes, int n_in,
                              void* d_out, int out_size, void* d_ws, size_t ws_size,
                              hipStream_t stream) {
    const float* x    = (const float*)d_in[0];
    const int*   mask = (const int*)d_in[1];
    const float* Wqkv = (const float*)d_in[2];
    const float* W1   = (const float*)d_in[3];
    const float* b1   = (const float*)d_in[4];
    const float* W2   = (const float*)d_in[5];
    const float* Wout = (const float*)d_in[6];
    float* out = (float*)d_out;
    char* ws = (char*)d_ws;

    unsigned short* wqkvT = (unsigned short*)(ws + 16777216);  // 1.5 MB [1536][512]
    unsigned short* woutT = (unsigned short*)(ws + 18350080);  // 0.5 MB [512][512]
    unsigned short* Qb    = (unsigned short*)(ws + 18874368);  // 16 MB [bh][l][d]
    unsigned short* Kb    = (unsigned short*)(ws + 35651584);  // 16 MB fragment-linear
    unsigned short* VTb   = (unsigned short*)(ws + 52428800);  // 16 MB fragment-linear
    unsigned short* AOb   = (unsigned short*)(ws + 69206016);  // 16 MB [16384][512]
    float* btab           = (float*)(ws + 85983232);           // 128 KB (tail region)
    if (ws_size < 86114304) return;

    k_prepw<<<264, 256, 0, stream>>>(Wqkv, wqkvT, Wout, woutT, W1, b1, W2, btab);
    k_gemm<0><<<dim3(12, 128), 256, 0, stream>>>(x, nullptr, wqkvT, 16384, 1536, Qb, Kb, VTb, nullptr);
    k_attn<<<512, 512, 0, stream>>>(Qb, Kb, VTb, mask, btab, AOb);
    k_gemm<1><<<dim3(4, 128), 256, 0, stream>>>(nullptr, AOb, woutT, 16384, 512, nullptr, nullptr, nullptr, out);
}